// Round 2
// baseline (637.882 us; speedup 1.0000x reference)
//
#include <hip/hip_runtime.h>

typedef unsigned short u16;
typedef __bf16 bf16x8 __attribute__((ext_vector_type(8)));
typedef float f32x4 __attribute__((ext_vector_type(4)));
typedef u16 u16x4 __attribute__((ext_vector_type(4)));

#define LOG2E_OVER_8 0.18033688011112043f

__device__ __forceinline__ u16 f2bf(float f) {
  union { float f; unsigned int u; } x{f};
  unsigned int r = (x.u + 0x7fffu + ((x.u >> 16) & 1u)) >> 16;
  return (u16)r;
}

__device__ __forceinline__ void gld16(const void* g, void* l) {
  __builtin_amdgcn_global_load_lds((const __attribute__((address_space(1))) unsigned int*)g,
                                   (__attribute__((address_space(3))) unsigned int*)l,
                                   16, 0, 0);
}

// ---------------- weight prep: W^T -> bf16 (Wq scaled, Wc = 8*Wg + Wbeta) ----
__global__ void prep_w(const float* __restrict__ Wq, const float* __restrict__ Wk,
                       const float* __restrict__ Wv, const float* __restrict__ Wg,
                       const float* __restrict__ Wb, const float* __restrict__ Wo,
                       u16* __restrict__ Wqt, u16* __restrict__ Wkt, u16* __restrict__ Wvt,
                       u16* __restrict__ Wct, u16* __restrict__ Wot)
{
  __shared__ float tile[32][33];
  const int m = blockIdx.z;
  const int nb = blockIdx.x * 32, kb = blockIdx.y * 32;
  const int tx = threadIdx.x, ty = threadIdx.y;
  const float* src = (m == 0) ? Wq : (m == 1) ? Wk : (m == 2) ? Wv : (m == 3) ? Wg : Wo;
  u16* dst = (m == 0) ? Wqt : (m == 1) ? Wkt : (m == 2) ? Wvt : (m == 3) ? Wct : Wot;
#pragma unroll
  for (int i = 0; i < 4; ++i) {
    const int k = kb + ty + i * 8;
    float v = src[k * 1024 + nb + tx];
    if (m == 3) v = 8.0f * v + Wb[k * 1024 + nb + tx];
    if (m == 0) v *= LOG2E_OVER_8;
    tile[ty + i * 8][tx] = v;
  }
  __syncthreads();
#pragma unroll
  for (int i = 0; i < 4; ++i) {
    const int r = ty + i * 8;
    dst[(nb + r) * 1024 + kb + tx] = f2bf(tile[tx][r]);
  }
}

__global__ void prep_b(const float* __restrict__ bq, const float* __restrict__ bg,
                       const float* __restrict__ bb,
                       float* __restrict__ bqs, float* __restrict__ bcs)
{
  const int i = blockIdx.x * 256 + threadIdx.x;
  if (i < 1024) {
    bqs[i] = bq[i] * LOG2E_OVER_8;
    bcs[i] = 8.0f * bg[i] + bb[i];
  }
}

// ---------------- f32 -> bf16 convert ----------------------------------------
__global__ void cvt_bf16(const float* __restrict__ in, u16* __restrict__ out, int n)
{
  int i = (blockIdx.x * blockDim.x + threadIdx.x) * 4;
  const int stride = gridDim.x * blockDim.x * 4;
  for (; i < n; i += stride) {
    const float4 v = *reinterpret_cast<const float4*>(in + i);
    u16x4 o;
    o.x = f2bf(v.x); o.y = f2bf(v.y); o.z = f2bf(v.z); o.w = f2bf(v.w);
    *reinterpret_cast<u16x4*>(out + i) = o;
  }
}

// ---------------- GEMM: C[8192x1024] = A[8192x1024] @ Bt^T + bias ------------
// Bt is [N=1024][K=1024] (pre-transposed weight). m97 structure: 128x128 tile,
// BK=32, 4 waves 2x2, global_load_lds width 16, 2-barrier K-loop.
// EPI: 0 = bf16 out; 1 = fp32 + bf16 out; 2 = bf16 out transposed per head
//      Vt[b][h][d][s]; 3 = fp32 out only.
template<int EPI>
__global__ __launch_bounds__(256, 2)
void gemm_k(const u16* __restrict__ A, const u16* __restrict__ Bt,
            const float* __restrict__ bias,
            u16* __restrict__ outb, float* __restrict__ outf)
{
  __shared__ u16 lA[128 * 32];
  __shared__ u16 lB[128 * 32];
  int bid = (int)blockIdx.x;
  bid = (bid & 7) * 64 + (bid >> 3);       // XCD-contiguous row bands (512 % 8 == 0)
  const int row0 = (bid >> 3) * 128;
  const int col0 = (bid & 7) * 128;
  const int t = threadIdx.x;
  const int w = t >> 6, lane = t & 63;
  const int l15 = lane & 15, l4 = lane >> 4;
  const int wr = w >> 1, wc = w & 1;

  const int c0 = t, c1 = 256 + t;
  const u16* gA0 = A + (row0 + (c0 >> 2)) * 1024 + (c0 & 3) * 8;
  const u16* gA1 = A + (row0 + (c1 >> 2)) * 1024 + (c1 & 3) * 8;
  const u16* gB0 = Bt + (col0 + (c0 >> 2)) * 1024 + (c0 & 3) * 8;
  const u16* gB1 = Bt + (col0 + (c1 >> 2)) * 1024 + (c1 & 3) * 8;
  u16* lA0 = lA + (w * 64) * 8;
  u16* lA1 = lA + (256 + w * 64) * 8;
  u16* lB0 = lB + (w * 64) * 8;
  u16* lB1 = lB + (256 + w * 64) * 8;

  f32x4 acc[4][4] = {};

  for (int kt = 0; kt < 1024; kt += 32) {
    gld16(gA0 + kt, lA0);
    gld16(gA1 + kt, lA1);
    gld16(gB0 + kt, lB0);
    gld16(gB1 + kt, lB1);
    __syncthreads();
    bf16x8 aF[4], bF[4];
#pragma unroll
    for (int m = 0; m < 4; ++m)
      aF[m] = *reinterpret_cast<const bf16x8*>(&lA[(wr * 64 + m * 16 + l15) * 32 + l4 * 8]);
#pragma unroll
    for (int n = 0; n < 4; ++n)
      bF[n] = *reinterpret_cast<const bf16x8*>(&lB[(wc * 64 + n * 16 + l15) * 32 + l4 * 8]);
#pragma unroll
    for (int m = 0; m < 4; ++m)
#pragma unroll
      for (int n = 0; n < 4; ++n)
        acc[m][n] = __builtin_amdgcn_mfma_f32_16x16x32_bf16(aF[m], bF[n], acc[m][n], 0, 0, 0);
    __syncthreads();
  }

  float bv[4];
#pragma unroll
  for (int n = 0; n < 4; ++n) bv[n] = bias[col0 + wc * 64 + n * 16 + l15];
#pragma unroll
  for (int m = 0; m < 4; ++m) {
#pragma unroll
    for (int n = 0; n < 4; ++n) {
      const int c = col0 + wc * 64 + n * 16 + l15;
#pragma unroll
      for (int j = 0; j < 4; ++j) {
        const int r = row0 + wr * 64 + m * 16 + l4 * 4 + j;
        const float v = acc[m][n][j] + bv[n];
        if constexpr (EPI == 0) {
          outb[r * 1024 + c] = f2bf(v);
        } else if constexpr (EPI == 1) {
          outf[r * 1024 + c] = v;
          outb[r * 1024 + c] = f2bf(v);
        } else if constexpr (EPI == 2) {
          const int bi = r >> 10, s = r & 1023;
          const int h = c >> 6, d = c & 63;
          outb[((bi * 16 + h) * 64 + d) * 1024 + s] = f2bf(v);
        } else {
          outf[r * 1024 + c] = v;
        }
      }
    }
  }
}

// ---------------- flash attention: Q,K [8192x1024] per-head cols, Vt[b][h][64][1024]
// scores pre-scaled by log2(e)/8 (folded into Wq/bq), softmax via exp2.
// launch_bounds(256,4): 4 blocks/CU co-resident (grid = 1024 = 4 per CU).
__global__ __launch_bounds__(256, 4)
void attn_k(const u16* __restrict__ Q, const u16* __restrict__ K,
            const u16* __restrict__ Vt, u16* __restrict__ ctx)
{
  __shared__ u16 P[4][32 * 72];   // per-wave P tile [32 q][64 kv], stride 72 (pad)
  const int qt = blockIdx.x, h = blockIdx.y, b = blockIdx.z;
  const int t = threadIdx.x, w = t >> 6, lane = t & 63;
  const int l15 = lane & 15, l4 = lane >> 4;
  const int q0 = qt * 128 + w * 32;
  const u16* Qp = Q + (size_t)b * 1024 * 1024 + h * 64;
  const u16* Kp = K + (size_t)b * 1024 * 1024 + h * 64;
  const u16* Vp = Vt + (size_t)(b * 16 + h) * 64 * 1024;
  u16* Pw = P[w];

  bf16x8 aQ[2][2];
#pragma unroll
  for (int qf = 0; qf < 2; ++qf)
#pragma unroll
    for (int ks = 0; ks < 2; ++ks)
      aQ[qf][ks] = *reinterpret_cast<const bf16x8*>(
          &Qp[(q0 + qf * 16 + l15) * 1024 + ks * 32 + l4 * 8]);

  f32x4 acc[2][4] = {};
  float mrow[2][4], lrow[2][4];
#pragma unroll
  for (int qf = 0; qf < 2; ++qf)
#pragma unroll
    for (int j = 0; j < 4; ++j) { mrow[qf][j] = -1e30f; lrow[qf][j] = 0.f; }

  for (int kv0 = 0; kv0 < 1024; kv0 += 64) {
    // S = Q K^T (pre-scaled); S-frag: col=kv(l15), row=q(l4*4+j)
    f32x4 s[2][4] = {};
#pragma unroll
    for (int ks = 0; ks < 2; ++ks) {
#pragma unroll
      for (int kf = 0; kf < 4; ++kf) {
        const bf16x8 bK = *reinterpret_cast<const bf16x8*>(
            &Kp[(kv0 + kf * 16 + l15) * 1024 + ks * 32 + l4 * 8]);
#pragma unroll
        for (int qf = 0; qf < 2; ++qf)
          s[qf][kf] = __builtin_amdgcn_mfma_f32_16x16x32_bf16(aQ[qf][ks], bK, s[qf][kf], 0, 0, 0);
      }
    }
    // early V issue: whole V tile into regs now; softmax below hides the latency
    bf16x8 vF[2][4];
#pragma unroll
    for (int kvs = 0; kvs < 2; ++kvs)
#pragma unroll
      for (int df = 0; df < 4; ++df)
        vF[kvs][df] = *reinterpret_cast<const bf16x8*>(
            &Vp[(df * 16 + l15) * 1024 + kv0 + kvs * 32 + l4 * 8]);
    // online softmax (row stats reduce over low-4 lane bits)
#pragma unroll
    for (int qf = 0; qf < 2; ++qf) {
      float psc[4];
#pragma unroll
      for (int j = 0; j < 4; ++j) {
        float tm = fmaxf(fmaxf(s[qf][0][j], s[qf][1][j]), fmaxf(s[qf][2][j], s[qf][3][j]));
        tm = fmaxf(tm, __shfl_xor(tm, 1));
        tm = fmaxf(tm, __shfl_xor(tm, 2));
        tm = fmaxf(tm, __shfl_xor(tm, 4));
        tm = fmaxf(tm, __shfl_xor(tm, 8));
        const float nm = fmaxf(mrow[qf][j], tm);
        psc[j] = __builtin_amdgcn_exp2f(mrow[qf][j] - nm);
        mrow[qf][j] = nm;
        float rs = 0.f;
#pragma unroll
        for (int kf = 0; kf < 4; ++kf) {
          const float p = __builtin_amdgcn_exp2f(s[qf][kf][j] - nm);
          s[qf][kf][j] = p;
          rs += p;
        }
        rs += __shfl_xor(rs, 1); rs += __shfl_xor(rs, 2);
        rs += __shfl_xor(rs, 4); rs += __shfl_xor(rs, 8);
        lrow[qf][j] = lrow[qf][j] * psc[j] + rs;
      }
#pragma unroll
      for (int df = 0; df < 4; ++df)
#pragma unroll
        for (int j = 0; j < 4; ++j) acc[qf][df][j] *= psc[j];
      // P -> LDS (bf16), layout [q][kv] so PV A-frag is contiguous b128
#pragma unroll
      for (int kf = 0; kf < 4; ++kf)
#pragma unroll
        for (int j = 0; j < 4; ++j)
          Pw[(qf * 16 + l4 * 4 + j) * 72 + kf * 16 + l15] = f2bf(s[qf][kf][j]);
    }
    // ctx += P @ V  (V already in regs)
#pragma unroll
    for (int kvs = 0; kvs < 2; ++kvs) {
      bf16x8 aP[2];
#pragma unroll
      for (int qf = 0; qf < 2; ++qf)
        aP[qf] = *reinterpret_cast<const bf16x8*>(&Pw[(qf * 16 + l15) * 72 + kvs * 32 + l4 * 8]);
#pragma unroll
      for (int df = 0; df < 4; ++df) {
#pragma unroll
        for (int qf = 0; qf < 2; ++qf)
          acc[qf][df] = __builtin_amdgcn_mfma_f32_16x16x32_bf16(aP[qf], vF[kvs][df], acc[qf][df], 0, 0, 0);
      }
    }
  }

  u16* Cp = ctx + (size_t)b * 1024 * 1024 + h * 64;
#pragma unroll
  for (int qf = 0; qf < 2; ++qf)
#pragma unroll
    for (int j = 0; j < 4; ++j) {
      const float inv = 1.0f / lrow[qf][j];
      const int r = q0 + qf * 16 + l4 * 4 + j;
#pragma unroll
      for (int df = 0; df < 4; ++df)
        Cp[r * 1024 + df * 16 + l15] = f2bf(acc[qf][df][j] * inv);
    }
}

// ---------------- driver ------------------------------------------------------
extern "C" void kernel_launch(void* const* d_in, const int* in_sizes, int n_in,
                              void* d_out, int out_size, void* d_ws, size_t ws_size,
                              hipStream_t stream)
{
  (void)in_sizes; (void)n_in; (void)out_size; (void)ws_size;
  const float* X  = (const float*)d_in[0];
  const float* Y  = (const float*)d_in[1];
  const float* Wq = (const float*)d_in[2];
  const float* bq = (const float*)d_in[3];
  const float* Wk = (const float*)d_in[4];
  const float* bk = (const float*)d_in[5];
  const float* Wv = (const float*)d_in[6];
  const float* bv = (const float*)d_in[7];
  const float* Wg = (const float*)d_in[8];
  const float* bg = (const float*)d_in[9];
  const float* Wb = (const float*)d_in[10];
  const float* bb = (const float*)d_in[11];
  const float* Wo = (const float*)d_in[12];
  const float* bo = (const float*)d_in[13];
  float* out = (float*)d_out;
  char* ws = (char*)d_ws;
  const size_t MB = 1024ull * 1024ull;

  u16* Wqt = (u16*)(ws + 0 * MB);
  u16* Wkt = (u16*)(ws + 2 * MB);
  u16* Wvt = (u16*)(ws + 4 * MB);
  u16* Wct = (u16*)(ws + 6 * MB);
  u16* Wot = (u16*)(ws + 8 * MB);
  float* bqs = (float*)(ws + 10 * MB);
  float* bcs = (float*)(ws + 10 * MB + 8192);
  u16* Xb = (u16*)(ws + 12 * MB);
  u16* Yb = (u16*)(ws + 28 * MB);   // original Y bf16; later reused for Y_new bf16
  u16* Qb = (u16*)(ws + 44 * MB);   // Q; later reused for mid
  u16* Kb = (u16*)(ws + 60 * MB);
  u16* Vt = (u16*)(ws + 76 * MB);
  u16* Cx = (u16*)(ws + 92 * MB);
  const int NEL = 8 * 1024 * 1024;

  prep_w<<<dim3(32, 32, 5), dim3(32, 8), 0, stream>>>(Wq, Wk, Wv, Wg, Wb, Wo,
                                                      Wqt, Wkt, Wvt, Wct, Wot);
  prep_b<<<4, 256, 0, stream>>>(bq, bg, bb, bqs, bcs);
  cvt_bf16<<<2048, 256, 0, stream>>>(X, Xb, NEL);
  cvt_bf16<<<2048, 256, 0, stream>>>(Y, Yb, NEL);

  // pass 1: queries from X, kv from Y  -> Y_new
  gemm_k<0><<<512, 256, 0, stream>>>(Xb, Wqt, bqs, Qb, nullptr);
  gemm_k<0><<<512, 256, 0, stream>>>(Yb, Wkt, bk, Kb, nullptr);
  gemm_k<2><<<512, 256, 0, stream>>>(Yb, Wvt, bv, Vt, nullptr);
  attn_k<<<dim3(8, 16, 8), 256, 0, stream>>>(Qb, Kb, Vt, Cx);
  gemm_k<0><<<512, 256, 0, stream>>>(Cx, Wct, bcs, Qb, nullptr);          // mid
  gemm_k<1><<<512, 256, 0, stream>>>(Qb, Wot, bo, Yb, out + NEL);          // Y_new (f32 + bf16)

  // pass 2: queries from Y_new, kv from X -> X_new
  gemm_k<0><<<512, 256, 0, stream>>>(Yb, Wqt, bqs, Qb, nullptr);
  gemm_k<0><<<512, 256, 0, stream>>>(Xb, Wkt, bk, Kb, nullptr);
  gemm_k<2><<<512, 256, 0, stream>>>(Xb, Wvt, bv, Vt, nullptr);
  attn_k<<<dim3(8, 16, 8), 256, 0, stream>>>(Qb, Kb, Vt, Cx);
  gemm_k<0><<<512, 256, 0, stream>>>(Cx, Wct, bcs, Qb, nullptr);          // mid
  gemm_k<3><<<512, 256, 0, stream>>>(Qb, Wot, bo, nullptr, out);          // X_new (f32)
}

// Round 3
// 495.726 us; speedup vs baseline: 1.2868x; 1.2868x over previous
//
#include <hip/hip_runtime.h>

typedef unsigned short u16;
typedef __bf16 bf16x8 __attribute__((ext_vector_type(8)));
typedef float f32x4 __attribute__((ext_vector_type(4)));
typedef u16 u16x4 __attribute__((ext_vector_type(4)));

#define LOG2E_OVER_8 0.18033688011112043f

__device__ __forceinline__ u16 f2bf(float f) {
  union { float f; unsigned int u; } x{f};
  unsigned int r = (x.u + 0x7fffu + ((x.u >> 16) & 1u)) >> 16;
  return (u16)r;
}

__device__ __forceinline__ void gld16(const void* g, void* l) {
  __builtin_amdgcn_global_load_lds((const __attribute__((address_space(1))) unsigned int*)g,
                                   (__attribute__((address_space(3))) unsigned int*)l,
                                   16, 0, 0);
}

// ---------------- weight prep: W^T -> bf16 (Wq scaled, Wc = 8*Wg + Wbeta) ----
__global__ void prep_w(const float* __restrict__ Wq, const float* __restrict__ Wk,
                       const float* __restrict__ Wv, const float* __restrict__ Wg,
                       const float* __restrict__ Wb, const float* __restrict__ Wo,
                       u16* __restrict__ Wqt, u16* __restrict__ Wkt, u16* __restrict__ Wvt,
                       u16* __restrict__ Wct, u16* __restrict__ Wot)
{
  __shared__ float tile[32][33];
  const int m = blockIdx.z;
  const int nb = blockIdx.x * 32, kb = blockIdx.y * 32;
  const int tx = threadIdx.x, ty = threadIdx.y;
  const float* src = (m == 0) ? Wq : (m == 1) ? Wk : (m == 2) ? Wv : (m == 3) ? Wg : Wo;
  u16* dst = (m == 0) ? Wqt : (m == 1) ? Wkt : (m == 2) ? Wvt : (m == 3) ? Wct : Wot;
#pragma unroll
  for (int i = 0; i < 4; ++i) {
    const int k = kb + ty + i * 8;
    float v = src[k * 1024 + nb + tx];
    if (m == 3) v = 8.0f * v + Wb[k * 1024 + nb + tx];
    if (m == 0) v *= LOG2E_OVER_8;
    tile[ty + i * 8][tx] = v;
  }
  __syncthreads();
#pragma unroll
  for (int i = 0; i < 4; ++i) {
    const int r = ty + i * 8;
    dst[(nb + r) * 1024 + kb + tx] = f2bf(tile[tx][r]);
  }
}

__global__ void prep_b(const float* __restrict__ bq, const float* __restrict__ bg,
                       const float* __restrict__ bb,
                       float* __restrict__ bqs, float* __restrict__ bcs)
{
  const int i = blockIdx.x * 256 + threadIdx.x;
  if (i < 1024) {
    bqs[i] = bq[i] * LOG2E_OVER_8;
    bcs[i] = 8.0f * bg[i] + bb[i];
  }
}

// ---------------- f32 -> bf16 convert ----------------------------------------
__global__ void cvt_bf16(const float* __restrict__ in, u16* __restrict__ out, int n)
{
  int i = (blockIdx.x * blockDim.x + threadIdx.x) * 4;
  const int stride = gridDim.x * blockDim.x * 4;
  for (; i < n; i += stride) {
    const float4 v = *reinterpret_cast<const float4*>(in + i);
    u16x4 o;
    o.x = f2bf(v.x); o.y = f2bf(v.y); o.z = f2bf(v.z); o.w = f2bf(v.w);
    *reinterpret_cast<u16x4*>(out + i) = o;
  }
}

// ---------------- GEMM: C[8192x1024] = A[8192x1024] @ Bt^T + bias ------------
// Bt is [N=1024][K=1024] (pre-transposed weight). m97 structure: 128x128 tile,
// BK=32, 4 waves 2x2, global_load_lds width 16, 2-barrier K-loop.
// EPI: 0 = bf16 out; 1 = fp32 + bf16 out; 2 = bf16 out transposed per head
//      Vt[b][h][d][s]; 3 = fp32 out only.
template<int EPI>
__global__ __launch_bounds__(256, 2)
void gemm_k(const u16* __restrict__ A, const u16* __restrict__ Bt,
            const float* __restrict__ bias,
            u16* __restrict__ outb, float* __restrict__ outf)
{
  __shared__ u16 lA[128 * 32];
  __shared__ u16 lB[128 * 32];
  int bid = (int)blockIdx.x;
  bid = (bid & 7) * 64 + (bid >> 3);       // XCD-contiguous row bands (512 % 8 == 0)
  const int row0 = (bid >> 3) * 128;
  const int col0 = (bid & 7) * 128;
  const int t = threadIdx.x;
  const int w = t >> 6, lane = t & 63;
  const int l15 = lane & 15, l4 = lane >> 4;
  const int wr = w >> 1, wc = w & 1;

  const int c0 = t, c1 = 256 + t;
  const u16* gA0 = A + (row0 + (c0 >> 2)) * 1024 + (c0 & 3) * 8;
  const u16* gA1 = A + (row0 + (c1 >> 2)) * 1024 + (c1 & 3) * 8;
  const u16* gB0 = Bt + (col0 + (c0 >> 2)) * 1024 + (c0 & 3) * 8;
  const u16* gB1 = Bt + (col0 + (c1 >> 2)) * 1024 + (c1 & 3) * 8;
  u16* lA0 = lA + (w * 64) * 8;
  u16* lA1 = lA + (256 + w * 64) * 8;
  u16* lB0 = lB + (w * 64) * 8;
  u16* lB1 = lB + (256 + w * 64) * 8;

  f32x4 acc[4][4] = {};

  for (int kt = 0; kt < 1024; kt += 32) {
    gld16(gA0 + kt, lA0);
    gld16(gA1 + kt, lA1);
    gld16(gB0 + kt, lB0);
    gld16(gB1 + kt, lB1);
    __syncthreads();
    bf16x8 aF[4], bF[4];
#pragma unroll
    for (int m = 0; m < 4; ++m)
      aF[m] = *reinterpret_cast<const bf16x8*>(&lA[(wr * 64 + m * 16 + l15) * 32 + l4 * 8]);
#pragma unroll
    for (int n = 0; n < 4; ++n)
      bF[n] = *reinterpret_cast<const bf16x8*>(&lB[(wc * 64 + n * 16 + l15) * 32 + l4 * 8]);
#pragma unroll
    for (int m = 0; m < 4; ++m)
#pragma unroll
      for (int n = 0; n < 4; ++n)
        acc[m][n] = __builtin_amdgcn_mfma_f32_16x16x32_bf16(aF[m], bF[n], acc[m][n], 0, 0, 0);
    __syncthreads();
  }

  float bv[4];
#pragma unroll
  for (int n = 0; n < 4; ++n) bv[n] = bias[col0 + wc * 64 + n * 16 + l15];
#pragma unroll
  for (int m = 0; m < 4; ++m) {
#pragma unroll
    for (int n = 0; n < 4; ++n) {
      const int c = col0 + wc * 64 + n * 16 + l15;
#pragma unroll
      for (int j = 0; j < 4; ++j) {
        const int r = row0 + wr * 64 + m * 16 + l4 * 4 + j;
        const float v = acc[m][n][j] + bv[n];
        if constexpr (EPI == 0) {
          outb[r * 1024 + c] = f2bf(v);
        } else if constexpr (EPI == 1) {
          outf[r * 1024 + c] = v;
          outb[r * 1024 + c] = f2bf(v);
        } else if constexpr (EPI == 2) {
          const int bi = r >> 10, s = r & 1023;
          const int h = c >> 6, d = c & 63;
          outb[((bi * 16 + h) * 64 + d) * 1024 + s] = f2bf(v);
        } else {
          outf[r * 1024 + c] = v;
        }
      }
    }
  }
}

// ---------------- flash attention v3 ------------------------------------------
// Q,K [8192x1024] per-head cols, Vt[b][h][64][1024]; scores pre-scaled by
// log2(e)/8 folded into Wq/bq, softmax via exp2.
// - K/V tiles staged in LDS ([64][72] pad: b128 read/write at bank floor),
//   shared by all 4 waves (4x fewer global loads than per-wave frags).
// - T14 async-stage: next tile's global loads issued right after the staging
//   barrier, consumed next iteration -> latency hidden under compute.
// - XCD swizzle: all 8 q-tile blocks of one (b,h) on the same XCD, adjacent
//   in dispatch order -> K/V L2-resident, fetched from HBM once.
__global__ __launch_bounds__(256, 3)
void attn_k(const u16* __restrict__ Q, const u16* __restrict__ K,
            const u16* __restrict__ Vt, u16* __restrict__ ctx)
{
  __shared__ u16 lK[64 * 72];
  __shared__ u16 lV[64 * 72];
  __shared__ u16 P[4][32 * 72];
  const int id = (int)blockIdx.x;
  const int xcd = id & 7, o = id >> 3;
  const int pair = xcd * 16 + (o >> 3);   // 16 (b,h) pairs per XCD
  const int qt = o & 7;
  const int b = pair >> 4, h = pair & 15;
  const int t = threadIdx.x, w = t >> 6, lane = t & 63;
  const int l15 = lane & 15, l4 = lane >> 4;
  const int q0 = qt * 128 + w * 32;
  const u16* Qp = Q + (size_t)b * (1024 * 1024) + h * 64;
  const u16* Kp = K + (size_t)b * (1024 * 1024) + h * 64;
  const u16* Vp = Vt + (size_t)(b * 16 + h) * (64 * 1024);
  u16* Pw = P[w];

  // staging slots: thread t owns rows r0 and r0+32, 16B chunk c0 (u16 units)
  const int r0 = t >> 3, c0 = (t & 7) * 8;

  bf16x8 aQ[2][2];
#pragma unroll
  for (int qf = 0; qf < 2; ++qf)
#pragma unroll
    for (int ks = 0; ks < 2; ++ks)
      aQ[qf][ks] = *reinterpret_cast<const bf16x8*>(
          &Qp[(q0 + qf * 16 + l15) * 1024 + ks * 32 + l4 * 8]);

  f32x4 acc[2][4] = {};
  float mrow[2][4], lrow[2][4];
#pragma unroll
  for (int qf = 0; qf < 2; ++qf)
#pragma unroll
    for (int j = 0; j < 4; ++j) { mrow[qf][j] = -1e30f; lrow[qf][j] = 0.f; }

  // prologue: issue tile-0 loads
  bf16x8 sK0, sK1, sV0, sV1;
  sK0 = *reinterpret_cast<const bf16x8*>(&Kp[(r0) * 1024 + c0]);
  sK1 = *reinterpret_cast<const bf16x8*>(&Kp[(r0 + 32) * 1024 + c0]);
  sV0 = *reinterpret_cast<const bf16x8*>(&Vp[r0 * 1024 + c0]);
  sV1 = *reinterpret_cast<const bf16x8*>(&Vp[(r0 + 32) * 1024 + c0]);

  for (int it = 0; it < 16; ++it) {
    const int kv0 = it * 64;
    __syncthreads();   // all waves done reading previous tile
    *reinterpret_cast<bf16x8*>(&lK[r0 * 72 + c0]) = sK0;
    *reinterpret_cast<bf16x8*>(&lK[(r0 + 32) * 72 + c0]) = sK1;
    *reinterpret_cast<bf16x8*>(&lV[r0 * 72 + c0]) = sV0;
    *reinterpret_cast<bf16x8*>(&lV[(r0 + 32) * 72 + c0]) = sV1;
    __syncthreads();   // tile ready
    if (it + 1 < 16) {  // issue next tile: in flight during the whole compute
      const int nk = kv0 + 64;
      sK0 = *reinterpret_cast<const bf16x8*>(&Kp[(nk + r0) * 1024 + c0]);
      sK1 = *reinterpret_cast<const bf16x8*>(&Kp[(nk + r0 + 32) * 1024 + c0]);
      sV0 = *reinterpret_cast<const bf16x8*>(&Vp[r0 * 1024 + nk + c0]);
      sV1 = *reinterpret_cast<const bf16x8*>(&Vp[(r0 + 32) * 1024 + nk + c0]);
    }

    // S = Q K^T (pre-scaled); S-frag: col=kv(l15), row=q(l4*4+j)
    f32x4 s[2][4] = {};
    __builtin_amdgcn_s_setprio(1);
#pragma unroll
    for (int ks = 0; ks < 2; ++ks) {
#pragma unroll
      for (int kf = 0; kf < 4; ++kf) {
        const bf16x8 bK = *reinterpret_cast<const bf16x8*>(
            &lK[(kf * 16 + l15) * 72 + ks * 32 + l4 * 8]);
        s[0][kf] = __builtin_amdgcn_mfma_f32_16x16x32_bf16(aQ[0][ks], bK, s[0][kf], 0, 0, 0);
        s[1][kf] = __builtin_amdgcn_mfma_f32_16x16x32_bf16(aQ[1][ks], bK, s[1][kf], 0, 0, 0);
      }
    }
    __builtin_amdgcn_s_setprio(0);

    // online softmax (row stats reduce over low-4 lane bits)
#pragma unroll
    for (int qf = 0; qf < 2; ++qf) {
      float psc[4];
#pragma unroll
      for (int j = 0; j < 4; ++j) {
        float tm = fmaxf(fmaxf(s[qf][0][j], s[qf][1][j]), fmaxf(s[qf][2][j], s[qf][3][j]));
        tm = fmaxf(tm, __shfl_xor(tm, 1));
        tm = fmaxf(tm, __shfl_xor(tm, 2));
        tm = fmaxf(tm, __shfl_xor(tm, 4));
        tm = fmaxf(tm, __shfl_xor(tm, 8));
        const float nm = fmaxf(mrow[qf][j], tm);
        psc[j] = __builtin_amdgcn_exp2f(mrow[qf][j] - nm);
        mrow[qf][j] = nm;
        float rs = 0.f;
#pragma unroll
        for (int kf = 0; kf < 4; ++kf) {
          const float p = __builtin_amdgcn_exp2f(s[qf][kf][j] - nm);
          s[qf][kf][j] = p;
          rs += p;
        }
        rs += __shfl_xor(rs, 1); rs += __shfl_xor(rs, 2);
        rs += __shfl_xor(rs, 4); rs += __shfl_xor(rs, 8);
        lrow[qf][j] = lrow[qf][j] * psc[j] + rs;
      }
#pragma unroll
      for (int df = 0; df < 4; ++df)
#pragma unroll
        for (int j = 0; j < 4; ++j) acc[qf][df][j] *= psc[j];
      // P -> LDS (bf16), layout [q][kv] so PV A-frag is contiguous b128
#pragma unroll
      for (int kf = 0; kf < 4; ++kf)
#pragma unroll
        for (int j = 0; j < 4; ++j)
          Pw[(qf * 16 + l4 * 4 + j) * 72 + kf * 16 + l15] = f2bf(s[qf][kf][j]);
    }

    // ctx += P @ V  (V from LDS)
#pragma unroll
    for (int kvs = 0; kvs < 2; ++kvs) {
      bf16x8 aP[2];
      aP[0] = *reinterpret_cast<const bf16x8*>(&Pw[(l15) * 72 + kvs * 32 + l4 * 8]);
      aP[1] = *reinterpret_cast<const bf16x8*>(&Pw[(16 + l15) * 72 + kvs * 32 + l4 * 8]);
      __builtin_amdgcn_s_setprio(1);
#pragma unroll
      for (int df = 0; df < 4; ++df) {
        const bf16x8 bV = *reinterpret_cast<const bf16x8*>(
            &lV[(df * 16 + l15) * 72 + kvs * 32 + l4 * 8]);
        acc[0][df] = __builtin_amdgcn_mfma_f32_16x16x32_bf16(aP[0], bV, acc[0][df], 0, 0, 0);
        acc[1][df] = __builtin_amdgcn_mfma_f32_16x16x32_bf16(aP[1], bV, acc[1][df], 0, 0, 0);
      }
      __builtin_amdgcn_s_setprio(0);
    }
  }

  u16* Cp = ctx + (size_t)b * (1024 * 1024) + h * 64;
#pragma unroll
  for (int qf = 0; qf < 2; ++qf)
#pragma unroll
    for (int j = 0; j < 4; ++j) {
      const float inv = 1.0f / lrow[qf][j];
      const int r = q0 + qf * 16 + l4 * 4 + j;
#pragma unroll
      for (int df = 0; df < 4; ++df)
        Cp[r * 1024 + df * 16 + l15] = f2bf(acc[qf][df][j] * inv);
    }
}

// ---------------- driver ------------------------------------------------------
extern "C" void kernel_launch(void* const* d_in, const int* in_sizes, int n_in,
                              void* d_out, int out_size, void* d_ws, size_t ws_size,
                              hipStream_t stream)
{
  (void)in_sizes; (void)n_in; (void)out_size; (void)ws_size;
  const float* X  = (const float*)d_in[0];
  const float* Y  = (const float*)d_in[1];
  const float* Wq = (const float*)d_in[2];
  const float* bq = (const float*)d_in[3];
  const float* Wk = (const float*)d_in[4];
  const float* bk = (const float*)d_in[5];
  const float* Wv = (const float*)d_in[6];
  const float* bv = (const float*)d_in[7];
  const float* Wg = (const float*)d_in[8];
  const float* bg = (const float*)d_in[9];
  const float* Wb = (const float*)d_in[10];
  const float* bb = (const float*)d_in[11];
  const float* Wo = (const float*)d_in[12];
  const float* bo = (const float*)d_in[13];
  float* out = (float*)d_out;
  char* ws = (char*)d_ws;
  const size_t MB = 1024ull * 1024ull;

  u16* Wqt = (u16*)(ws + 0 * MB);
  u16* Wkt = (u16*)(ws + 2 * MB);
  u16* Wvt = (u16*)(ws + 4 * MB);
  u16* Wct = (u16*)(ws + 6 * MB);
  u16* Wot = (u16*)(ws + 8 * MB);
  float* bqs = (float*)(ws + 10 * MB);
  float* bcs = (float*)(ws + 10 * MB + 8192);
  u16* Xb = (u16*)(ws + 12 * MB);
  u16* Yb = (u16*)(ws + 28 * MB);   // original Y bf16; later reused for Y_new bf16
  u16* Qb = (u16*)(ws + 44 * MB);   // Q; later reused for mid
  u16* Kb = (u16*)(ws + 60 * MB);
  u16* Vt = (u16*)(ws + 76 * MB);
  u16* Cx = (u16*)(ws + 92 * MB);
  const int NEL = 8 * 1024 * 1024;

  prep_w<<<dim3(32, 32, 5), dim3(32, 8), 0, stream>>>(Wq, Wk, Wv, Wg, Wb, Wo,
                                                      Wqt, Wkt, Wvt, Wct, Wot);
  prep_b<<<4, 256, 0, stream>>>(bq, bg, bb, bqs, bcs);
  cvt_bf16<<<2048, 256, 0, stream>>>(X, Xb, NEL);
  cvt_bf16<<<2048, 256, 0, stream>>>(Y, Yb, NEL);

  // pass 1: queries from X, kv from Y  -> Y_new
  gemm_k<0><<<512, 256, 0, stream>>>(Xb, Wqt, bqs, Qb, nullptr);
  gemm_k<0><<<512, 256, 0, stream>>>(Yb, Wkt, bk, Kb, nullptr);
  gemm_k<2><<<512, 256, 0, stream>>>(Yb, Wvt, bv, Vt, nullptr);
  attn_k<<<dim3(1024), 256, 0, stream>>>(Qb, Kb, Vt, Cx);
  gemm_k<0><<<512, 256, 0, stream>>>(Cx, Wct, bcs, Qb, nullptr);          // mid
  gemm_k<1><<<512, 256, 0, stream>>>(Qb, Wot, bo, Yb, out + NEL);          // Y_new (f32 + bf16)

  // pass 2: queries from Y_new, kv from X -> X_new
  gemm_k<0><<<512, 256, 0, stream>>>(Yb, Wqt, bqs, Qb, nullptr);
  gemm_k<0><<<512, 256, 0, stream>>>(Xb, Wkt, bk, Kb, nullptr);
  gemm_k<2><<<512, 256, 0, stream>>>(Xb, Wvt, bv, Vt, nullptr);
  attn_k<<<dim3(1024), 256, 0, stream>>>(Qb, Kb, Vt, Cx);
  gemm_k<0><<<512, 256, 0, stream>>>(Cx, Wct, bcs, Qb, nullptr);          // mid
  gemm_k<3><<<512, 256, 0, stream>>>(Qb, Wot, bo, nullptr, out);          // X_new (f32)
}

// Round 6
// 437.569 us; speedup vs baseline: 1.4578x; 1.1329x over previous
//
#include <hip/hip_runtime.h>

typedef unsigned short u16;
typedef __bf16 bf16x8 __attribute__((ext_vector_type(8)));
typedef float f32x4 __attribute__((ext_vector_type(4)));
typedef u16 u16x4 __attribute__((ext_vector_type(4)));

#define LOG2E_OVER_8 0.18033688011112043f

__device__ __forceinline__ u16 f2bf(float f) {
  union { float f; unsigned int u; } x{f};
  unsigned int r = (x.u + 0x7fffu + ((x.u >> 16) & 1u)) >> 16;
  return (u16)r;
}

__device__ __forceinline__ void gld16(const void* g, void* l) {
  __builtin_amdgcn_global_load_lds((const __attribute__((address_space(1))) unsigned int*)g,
                                   (__attribute__((address_space(3))) unsigned int*)l,
                                   16, 0, 0);
}

// ---------------- weight prep -------------------------------------------------
// m=0: Wqt = (Wq*log2e/8)^T   m=1: Wkt = Wk^T   m=2: Wvt = Wv^T
// m=3: Wcn = 8*Wg + Wbeta, NON-transposed bf16 (B-input of the Wco fusion GEMM)
// m=4: Wot = Wo^T
__global__ void prep_w(const float* __restrict__ Wq, const float* __restrict__ Wk,
                       const float* __restrict__ Wv, const float* __restrict__ Wg,
                       const float* __restrict__ Wb, const float* __restrict__ Wo,
                       u16* __restrict__ Wqt, u16* __restrict__ Wkt, u16* __restrict__ Wvt,
                       u16* __restrict__ Wcn, u16* __restrict__ Wot)
{
  __shared__ float tile[32][33];
  const int m = blockIdx.z;
  const int nb = blockIdx.x * 32, kb = blockIdx.y * 32;
  const int tx = threadIdx.x, ty = threadIdx.y;
  const float* src = (m == 0) ? Wq : (m == 1) ? Wk : (m == 2) ? Wv : (m == 3) ? Wg : Wo;
  u16* dst = (m == 0) ? Wqt : (m == 1) ? Wkt : (m == 2) ? Wvt : (m == 3) ? Wcn : Wot;
#pragma unroll
  for (int i = 0; i < 4; ++i) {
    const int k = kb + ty + i * 8;
    float v = src[k * 1024 + nb + tx];
    if (m == 3) v = 8.0f * v + Wb[k * 1024 + nb + tx];
    if (m == 0) v *= LOG2E_OVER_8;
    if (m == 3) dst[k * 1024 + nb + tx] = f2bf(v);   // direct, non-transposed
    else        tile[ty + i * 8][tx] = v;
  }
  __syncthreads();
  if (m != 3) {
#pragma unroll
    for (int i = 0; i < 4; ++i) {
      const int r = ty + i * 8;
      dst[(nb + r) * 1024 + kb + tx] = f2bf(tile[tx][r]);
    }
  }
}

__global__ void prep_b(const float* __restrict__ bq, const float* __restrict__ bg,
                       const float* __restrict__ bb,
                       float* __restrict__ bqs, float* __restrict__ bcs)
{
  const int i = blockIdx.x * 256 + threadIdx.x;
  if (i < 1024) {
    bqs[i] = bq[i] * LOG2E_OVER_8;
    bcs[i] = 8.0f * bg[i] + bb[i];
  }
}

// bco[n] = sum_m bcs[m] * Wo[m][n] + bo[n]
__global__ void fuse_bias(const float* __restrict__ bcs, const float* __restrict__ Wo,
                          const float* __restrict__ bo, float* __restrict__ bco)
{
  const int n = blockIdx.x * 256 + threadIdx.x;
  float a = bo[n];
  for (int m = 0; m < 1024; ++m) a += bcs[m] * Wo[m * 1024 + n];
  bco[n] = a;
}

// ---------------- f32 -> bf16 convert ----------------------------------------
__global__ void cvt_bf16(const float* __restrict__ in, u16* __restrict__ out, int n)
{
  int i = (blockIdx.x * blockDim.x + threadIdx.x) * 4;
  const int stride = gridDim.x * blockDim.x * 4;
  for (; i < n; i += stride) {
    const float4 v = *reinterpret_cast<const float4*>(in + i);
    u16x4 o;
    o.x = f2bf(v.x); o.y = f2bf(v.y); o.z = f2bf(v.z); o.w = f2bf(v.w);
    *reinterpret_cast<u16x4*>(out + i) = o;
  }
}

// ---------------- GEMM: C[NB*128 x 1024] = A @ Bt^T + bias --------------------
// Bt is [N=1024][K=1024] (pre-transposed weight). m97 structure: 128x128 tile,
// BK=32, 4 waves 2x2, global_load_lds width 16, 2-barrier K-loop.
// EPI: 0 = bf16 out; 1 = fp32 + bf16 out; 2 = bf16 out transposed per head
//      Vt[b][h][d][s]; 3 = fp32 out only; 4 = bf16 out, NO bias.
// NB = number of 128-row blocks (grid = NB*8).
template<int EPI, int NB = 64>
__global__ __launch_bounds__(256, 2)
void gemm_k(const u16* __restrict__ A, const u16* __restrict__ Bt,
            const float* __restrict__ bias,
            u16* __restrict__ outb, float* __restrict__ outf)
{
  __shared__ u16 lA[128 * 32];
  __shared__ u16 lB[128 * 32];
  int bid = (int)blockIdx.x;
  bid = (bid & 7) * NB + (bid >> 3);       // XCD-contiguous row bands (grid%8==0)
  const int row0 = (bid >> 3) * 128;
  const int col0 = (bid & 7) * 128;
  const int t = threadIdx.x;
  const int w = t >> 6, lane = t & 63;
  const int l15 = lane & 15, l4 = lane >> 4;
  const int wr = w >> 1, wc = w & 1;

  const int c0 = t, c1 = 256 + t;
  const u16* gA0 = A + (row0 + (c0 >> 2)) * 1024 + (c0 & 3) * 8;
  const u16* gA1 = A + (row0 + (c1 >> 2)) * 1024 + (c1 & 3) * 8;
  const u16* gB0 = Bt + (col0 + (c0 >> 2)) * 1024 + (c0 & 3) * 8;
  const u16* gB1 = Bt + (col0 + (c1 >> 2)) * 1024 + (c1 & 3) * 8;
  u16* lA0 = lA + (w * 64) * 8;
  u16* lA1 = lA + (256 + w * 64) * 8;
  u16* lB0 = lB + (w * 64) * 8;
  u16* lB1 = lB + (256 + w * 64) * 8;

  f32x4 acc[4][4] = {};

  for (int kt = 0; kt < 1024; kt += 32) {
    gld16(gA0 + kt, lA0);
    gld16(gA1 + kt, lA1);
    gld16(gB0 + kt, lB0);
    gld16(gB1 + kt, lB1);
    __syncthreads();
    bf16x8 aF[4], bF[4];
#pragma unroll
    for (int m = 0; m < 4; ++m)
      aF[m] = *reinterpret_cast<const bf16x8*>(&lA[(wr * 64 + m * 16 + l15) * 32 + l4 * 8]);
#pragma unroll
    for (int n = 0; n < 4; ++n)
      bF[n] = *reinterpret_cast<const bf16x8*>(&lB[(wc * 64 + n * 16 + l15) * 32 + l4 * 8]);
#pragma unroll
    for (int m = 0; m < 4; ++m)
#pragma unroll
      for (int n = 0; n < 4; ++n)
        acc[m][n] = __builtin_amdgcn_mfma_f32_16x16x32_bf16(aF[m], bF[n], acc[m][n], 0, 0, 0);
    __syncthreads();
  }

  float bv[4];
#pragma unroll
  for (int n = 0; n < 4; ++n)
    bv[n] = (EPI == 4) ? 0.0f : bias[col0 + wc * 64 + n * 16 + l15];
#pragma unroll
  for (int m = 0; m < 4; ++m) {
#pragma unroll
    for (int n = 0; n < 4; ++n) {
      const int c = col0 + wc * 64 + n * 16 + l15;
#pragma unroll
      for (int j = 0; j < 4; ++j) {
        const int r = row0 + wr * 64 + m * 16 + l4 * 4 + j;
        const float v = acc[m][n][j] + bv[n];
        if constexpr (EPI == 0 || EPI == 4) {
          outb[r * 1024 + c] = f2bf(v);
        } else if constexpr (EPI == 1) {
          outf[r * 1024 + c] = v;
          outb[r * 1024 + c] = f2bf(v);
        } else if constexpr (EPI == 2) {
          const int bi = r >> 10, s = r & 1023;
          const int h = c >> 6, d = c & 63;
          outb[((bi * 16 + h) * 64 + d) * 1024 + s] = f2bf(v);
        } else {
          outf[r * 1024 + c] = v;
        }
      }
    }
  }
}

// ---------------- flash attention v4 ------------------------------------------
// Q,K [8192x1024] per-head cols, Vt[b][h][64][1024]; scores pre-scaled by
// log2(e)/8 folded into Wq/bq, softmax via exp2.
// - K/V tiles staged in LDS, T14 async-stage, XCD co-location (as v3).
// - Wave-uniform tile max (31 fmax + 6 shfl) instead of per-row reductions.
// - Row sums via ones-column MFMA (lsum accumulated in the matrix pipe).
// - P-tile XOR swizzle (col ^= ((row>>2)&3)<<3) -> conflict-free writes/reads.
__global__ __launch_bounds__(256, 3)
void attn_k(const u16* __restrict__ Q, const u16* __restrict__ K,
            const u16* __restrict__ Vt, u16* __restrict__ ctx)
{
  __shared__ u16 lK[64 * 72];
  __shared__ u16 lV[64 * 72];
  __shared__ u16 P[4][32 * 72];
  const int id = (int)blockIdx.x;
  const int xcd = id & 7, o = id >> 3;
  const int pair = xcd * 16 + (o >> 3);   // 16 (b,h) pairs per XCD
  const int qt = o & 7;
  const int b = pair >> 4, h = pair & 15;
  const int t = threadIdx.x, w = t >> 6, lane = t & 63;
  const int l15 = lane & 15, l4 = lane >> 4;
  const int q0 = qt * 128 + w * 32;
  const u16* Qp = Q + (size_t)b * (1024 * 1024) + h * 64;
  const u16* Kp = K + (size_t)b * (1024 * 1024) + h * 64;
  const u16* Vp = Vt + (size_t)(b * 16 + h) * (64 * 1024);
  u16* Pw = P[w];

  // staging slots: thread t owns rows r0 and r0+32, 16B chunk c0 (u16 units)
  const int r0 = t >> 3, c0 = (t & 7) * 8;

  bf16x8 aQ[2][2];
#pragma unroll
  for (int qf = 0; qf < 2; ++qf)
#pragma unroll
    for (int ks = 0; ks < 2; ++ks)
      aQ[qf][ks] = *reinterpret_cast<const bf16x8*>(
          &Qp[(q0 + qf * 16 + l15) * 1024 + ks * 32 + l4 * 8]);

  // ones-column B fragment: B[k][n]=1 iff n==0 -> lanes with l15==0 hold 1.0
  bf16x8 bOnes = {};
  if (l15 == 0) {
#pragma unroll
    for (int i = 0; i < 8; ++i) bOnes[i] = (__bf16)1.0f;
  }

  f32x4 acc[2][4] = {};
  f32x4 lsum[2] = {};
  float m_run = -3.0e38f;

  // prologue: issue tile-0 loads
  bf16x8 sK0, sK1, sV0, sV1;
  sK0 = *reinterpret_cast<const bf16x8*>(&Kp[(r0) * 1024 + c0]);
  sK1 = *reinterpret_cast<const bf16x8*>(&Kp[(r0 + 32) * 1024 + c0]);
  sV0 = *reinterpret_cast<const bf16x8*>(&Vp[r0 * 1024 + c0]);
  sV1 = *reinterpret_cast<const bf16x8*>(&Vp[(r0 + 32) * 1024 + c0]);

  for (int it = 0; it < 16; ++it) {
    const int kv0 = it * 64;
    __syncthreads();   // all waves done reading previous tile
    *reinterpret_cast<bf16x8*>(&lK[r0 * 72 + c0]) = sK0;
    *reinterpret_cast<bf16x8*>(&lK[(r0 + 32) * 72 + c0]) = sK1;
    *reinterpret_cast<bf16x8*>(&lV[r0 * 72 + c0]) = sV0;
    *reinterpret_cast<bf16x8*>(&lV[(r0 + 32) * 72 + c0]) = sV1;
    __syncthreads();   // tile ready
    if (it + 1 < 16) {  // issue next tile: in flight during the whole compute
      const int nk = kv0 + 64;
      sK0 = *reinterpret_cast<const bf16x8*>(&Kp[(nk + r0) * 1024 + c0]);
      sK1 = *reinterpret_cast<const bf16x8*>(&Kp[(nk + r0 + 32) * 1024 + c0]);
      sV0 = *reinterpret_cast<const bf16x8*>(&Vp[r0 * 1024 + nk + c0]);
      sV1 = *reinterpret_cast<const bf16x8*>(&Vp[(r0 + 32) * 1024 + nk + c0]);
    }

    // S = Q K^T (pre-scaled); S-frag: col=kv(l15), row=q(l4*4+j)
    f32x4 s[2][4] = {};
    __builtin_amdgcn_s_setprio(1);
#pragma unroll
    for (int ks = 0; ks < 2; ++ks) {
#pragma unroll
      for (int kf = 0; kf < 4; ++kf) {
        const bf16x8 bK = *reinterpret_cast<const bf16x8*>(
            &lK[(kf * 16 + l15) * 72 + ks * 32 + l4 * 8]);
        s[0][kf] = __builtin_amdgcn_mfma_f32_16x16x32_bf16(aQ[0][ks], bK, s[0][kf], 0, 0, 0);
        s[1][kf] = __builtin_amdgcn_mfma_f32_16x16x32_bf16(aQ[1][ks], bK, s[1][kf], 0, 0, 0);
      }
    }
    __builtin_amdgcn_s_setprio(0);

    // wave-uniform tile max
    float tm = -3.0e38f;
#pragma unroll
    for (int qf = 0; qf < 2; ++qf)
#pragma unroll
      for (int kf = 0; kf < 4; ++kf)
        tm = fmaxf(tm, fmaxf(fmaxf(s[qf][kf][0], s[qf][kf][1]),
                             fmaxf(s[qf][kf][2], s[qf][kf][3])));
#pragma unroll
    for (int d = 1; d < 64; d <<= 1) tm = fmaxf(tm, __shfl_xor(tm, d));
    const float nm = fmaxf(m_run, tm);
    const float psc = __builtin_amdgcn_exp2f(m_run - nm);
    m_run = nm;

    // P = exp2(S - nm), write to LDS with XOR swizzle; rescale acc & lsum
#pragma unroll
    for (int qf = 0; qf < 2; ++qf) {
#pragma unroll
      for (int kf = 0; kf < 4; ++kf) {
        const int pc = (kf * 16 + l15) ^ (l4 << 3);
#pragma unroll
        for (int j = 0; j < 4; ++j) {
          const float p = __builtin_amdgcn_exp2f(s[qf][kf][j] - nm);
          Pw[(qf * 16 + l4 * 4 + j) * 72 + pc] = f2bf(p);
        }
      }
#pragma unroll
      for (int df = 0; df < 4; ++df)
#pragma unroll
        for (int j = 0; j < 4; ++j) acc[qf][df][j] *= psc;
#pragma unroll
      for (int j = 0; j < 4; ++j) lsum[qf][j] *= psc;
    }

    // ctx += P @ V ; lsum += P @ ones  (both in the MFMA pipe)
#pragma unroll
    for (int kvs = 0; kvs < 2; ++kvs) {
      const int pr = (kvs * 32 + l4 * 8) ^ ((l15 >> 2) << 3);
      bf16x8 aP[2];
      aP[0] = *reinterpret_cast<const bf16x8*>(&Pw[(l15) * 72 + pr]);
      aP[1] = *reinterpret_cast<const bf16x8*>(&Pw[(16 + l15) * 72 + pr]);
      __builtin_amdgcn_s_setprio(1);
#pragma unroll
      for (int df = 0; df < 4; ++df) {
        const bf16x8 bV = *reinterpret_cast<const bf16x8*>(
            &lV[(df * 16 + l15) * 72 + kvs * 32 + l4 * 8]);
        acc[0][df] = __builtin_amdgcn_mfma_f32_16x16x32_bf16(aP[0], bV, acc[0][df], 0, 0, 0);
        acc[1][df] = __builtin_amdgcn_mfma_f32_16x16x32_bf16(aP[1], bV, acc[1][df], 0, 0, 0);
      }
      lsum[0] = __builtin_amdgcn_mfma_f32_16x16x32_bf16(aP[0], bOnes, lsum[0], 0, 0, 0);
      lsum[1] = __builtin_amdgcn_mfma_f32_16x16x32_bf16(aP[1], bOnes, lsum[1], 0, 0, 0);
      __builtin_amdgcn_s_setprio(0);
    }
  }

  // row sums live in lanes l15==0 (lane = l4*16), row = l4*4+j -> broadcast
  u16* Cp = ctx + (size_t)b * (1024 * 1024) + h * 64;
#pragma unroll
  for (int qf = 0; qf < 2; ++qf)
#pragma unroll
    for (int j = 0; j < 4; ++j) {
      const float lr = __shfl(lsum[qf][j], (lane & 48));
      const float inv = 1.0f / lr;
      const int r = q0 + qf * 16 + l4 * 4 + j;
#pragma unroll
      for (int df = 0; df < 4; ++df)
        Cp[r * 1024 + df * 16 + l15] = f2bf(acc[qf][df][j] * inv);
    }
}

// ---------------- driver ------------------------------------------------------
extern "C" void kernel_launch(void* const* d_in, const int* in_sizes, int n_in,
                              void* d_out, int out_size, void* d_ws, size_t ws_size,
                              hipStream_t stream)
{
  (void)in_sizes; (void)n_in; (void)out_size; (void)ws_size;
  const float* X  = (const float*)d_in[0];
  const float* Y  = (const float*)d_in[1];
  const float* Wq = (const float*)d_in[2];
  const float* bq = (const float*)d_in[3];
  const float* Wk = (const float*)d_in[4];
  const float* bk = (const float*)d_in[5];
  const float* Wv = (const float*)d_in[6];
  const float* bv = (const float*)d_in[7];
  const float* Wg = (const float*)d_in[8];
  const float* bg = (const float*)d_in[9];
  const float* Wb = (const float*)d_in[10];
  const float* bb = (const float*)d_in[11];
  const float* Wo = (const float*)d_in[12];
  const float* bo = (const float*)d_in[13];
  float* out = (float*)d_out;
  char* ws = (char*)d_ws;
  const size_t MB = 1024ull * 1024ull;

  u16* Wqt = (u16*)(ws + 0 * MB);
  u16* Wkt = (u16*)(ws + 2 * MB);
  u16* Wvt = (u16*)(ws + 4 * MB);
  u16* Wcn = (u16*)(ws + 6 * MB);    // Wc = 8*Wg+Wb, non-transposed bf16
  u16* Wot = (u16*)(ws + 8 * MB);
  u16* Wcot = (u16*)(ws + 10 * MB);  // (Wc @ Wo)^T bf16
  u16* Xb = (u16*)(ws + 12 * MB);
  u16* Yb = (u16*)(ws + 28 * MB);   // original Y bf16; later reused for Y_new bf16
  u16* Qb = (u16*)(ws + 44 * MB);
  u16* Kb = (u16*)(ws + 60 * MB);
  u16* Vt = (u16*)(ws + 76 * MB);
  u16* Cx = (u16*)(ws + 92 * MB);
  float* bqs = (float*)(ws + 108 * MB);
  float* bcs = (float*)(ws + 108 * MB + 4096);
  float* bco = (float*)(ws + 108 * MB + 8192);
  const int NEL = 8 * 1024 * 1024;

  prep_w<<<dim3(32, 32, 5), dim3(32, 8), 0, stream>>>(Wq, Wk, Wv, Wg, Wb, Wo,
                                                      Wqt, Wkt, Wvt, Wcn, Wot);
  prep_b<<<4, 256, 0, stream>>>(bq, bg, bb, bqs, bcs);
  fuse_bias<<<4, 256, 0, stream>>>(bcs, Wo, bo, bco);
  // Wcot[r][c] = sum_k Wot[r][k]*Wcn[c][k] = (Wc@Wo)^T, no bias
  gemm_k<4, 8><<<64, 256, 0, stream>>>(Wot, Wcn, nullptr, Wcot, nullptr);
  cvt_bf16<<<2048, 256, 0, stream>>>(X, Xb, NEL);
  cvt_bf16<<<2048, 256, 0, stream>>>(Y, Yb, NEL);

  // pass 1: queries from X, kv from Y  -> Y_new
  gemm_k<0><<<512, 256, 0, stream>>>(Xb, Wqt, bqs, Qb, nullptr);
  gemm_k<0><<<512, 256, 0, stream>>>(Yb, Wkt, bk, Kb, nullptr);
  gemm_k<2><<<512, 256, 0, stream>>>(Yb, Wvt, bv, Vt, nullptr);
  attn_k<<<dim3(1024), 256, 0, stream>>>(Qb, Kb, Vt, Cx);
  gemm_k<1><<<512, 256, 0, stream>>>(Cx, Wcot, bco, Yb, out + NEL);   // Y_new (f32+bf16)

  // pass 2: queries from Y_new, kv from X -> X_new
  gemm_k<0><<<512, 256, 0, stream>>>(Yb, Wqt, bqs, Qb, nullptr);
  gemm_k<0><<<512, 256, 0, stream>>>(Xb, Wkt, bk, Kb, nullptr);
  gemm_k<2><<<512, 256, 0, stream>>>(Xb, Wvt, bv, Vt, nullptr);
  attn_k<<<dim3(1024), 256, 0, stream>>>(Qb, Kb, Vt, Cx);
  gemm_k<3><<<512, 256, 0, stream>>>(Cx, Wcot, bco, nullptr, out);    // X_new (f32)
}

// Round 7
// 421.746 us; speedup vs baseline: 1.5125x; 1.0375x over previous
//
#include <hip/hip_runtime.h>

typedef unsigned short u16;
typedef __bf16 bf16x8 __attribute__((ext_vector_type(8)));
typedef float f32x4 __attribute__((ext_vector_type(4)));
typedef float f32x16 __attribute__((ext_vector_type(16)));
typedef u16 u16x4 __attribute__((ext_vector_type(4)));
typedef unsigned int u32x4v __attribute__((ext_vector_type(4)));

#define LOG2E_OVER_8 0.18033688011112043f

__device__ __forceinline__ u16 f2bf(float f) {
  union { float f; unsigned int u; } x{f};
  unsigned int r = (x.u + 0x7fffu + ((x.u >> 16) & 1u)) >> 16;
  return (u16)r;
}

__device__ __forceinline__ unsigned cvtpk(float a, float b) {
  unsigned r;
  asm("v_cvt_pk_bf16_f32 %0, %1, %2" : "=v"(r) : "v"(a), "v"(b));
  return r;
}

__device__ __forceinline__ void gld16(const void* g, void* l) {
  __builtin_amdgcn_global_load_lds((const __attribute__((address_space(1))) unsigned int*)g,
                                   (__attribute__((address_space(3))) unsigned int*)l,
                                   16, 0, 0);
}

// ---------------- weight prep -------------------------------------------------
// m=0: Wqt = (Wq*log2e/8)^T   m=1: Wkt = Wk^T   m=2: Wvt = Wv^T
// m=3: Wcn = 8*Wg + Wbeta, NON-transposed bf16   m=4: Wot = Wo^T
__global__ void prep_w(const float* __restrict__ Wq, const float* __restrict__ Wk,
                       const float* __restrict__ Wv, const float* __restrict__ Wg,
                       const float* __restrict__ Wb, const float* __restrict__ Wo,
                       u16* __restrict__ Wqt, u16* __restrict__ Wkt, u16* __restrict__ Wvt,
                       u16* __restrict__ Wcn, u16* __restrict__ Wot)
{
  __shared__ float tile[32][33];
  const int m = blockIdx.z;
  const int nb = blockIdx.x * 32, kb = blockIdx.y * 32;
  const int tx = threadIdx.x, ty = threadIdx.y;
  const float* src = (m == 0) ? Wq : (m == 1) ? Wk : (m == 2) ? Wv : (m == 3) ? Wg : Wo;
  u16* dst = (m == 0) ? Wqt : (m == 1) ? Wkt : (m == 2) ? Wvt : (m == 3) ? Wcn : Wot;
#pragma unroll
  for (int i = 0; i < 4; ++i) {
    const int k = kb + ty + i * 8;
    float v = src[k * 1024 + nb + tx];
    if (m == 3) v = 8.0f * v + Wb[k * 1024 + nb + tx];
    if (m == 0) v *= LOG2E_OVER_8;
    if (m == 3) dst[k * 1024 + nb + tx] = f2bf(v);   // direct, non-transposed
    else        tile[ty + i * 8][tx] = v;
  }
  __syncthreads();
  if (m != 3) {
#pragma unroll
    for (int i = 0; i < 4; ++i) {
      const int r = ty + i * 8;
      dst[(nb + r) * 1024 + kb + tx] = f2bf(tile[tx][r]);
    }
  }
}

__global__ void prep_b(const float* __restrict__ bq, const float* __restrict__ bg,
                       const float* __restrict__ bb,
                       float* __restrict__ bqs, float* __restrict__ bcs)
{
  const int i = blockIdx.x * 256 + threadIdx.x;
  if (i < 1024) {
    bqs[i] = bq[i] * LOG2E_OVER_8;
    bcs[i] = 8.0f * bg[i] + bb[i];
  }
}

// bco[n] = sum_m bcs[m] * Wo[m][n] + bo[n]
__global__ void fuse_bias(const float* __restrict__ bcs, const float* __restrict__ Wo,
                          const float* __restrict__ bo, float* __restrict__ bco)
{
  const int n = blockIdx.x * 256 + threadIdx.x;
  float a = bo[n];
  for (int m = 0; m < 1024; ++m) a += bcs[m] * Wo[m * 1024 + n];
  bco[n] = a;
}

// ---------------- f32 -> bf16 convert ----------------------------------------
__global__ void cvt_bf16(const float* __restrict__ in, u16* __restrict__ out, int n)
{
  int i = (blockIdx.x * blockDim.x + threadIdx.x) * 4;
  const int stride = gridDim.x * blockDim.x * 4;
  for (; i < n; i += stride) {
    const float4 v = *reinterpret_cast<const float4*>(in + i);
    u16x4 o;
    o.x = f2bf(v.x); o.y = f2bf(v.y); o.z = f2bf(v.z); o.w = f2bf(v.w);
    *reinterpret_cast<u16x4*>(out + i) = o;
  }
}

// ---------------- GEMM: C[NB*128 x 1024] = A @ Bt^T + bias --------------------
// EPI: 0 = bf16 out; 1 = fp32 + bf16 out; 2 = bf16 out transposed per head
//      Vt[b][h][d][s]; 3 = fp32 out only; 4 = bf16 out, NO bias.
template<int EPI, int NB = 64>
__global__ __launch_bounds__(256, 2)
void gemm_k(const u16* __restrict__ A, const u16* __restrict__ Bt,
            const float* __restrict__ bias,
            u16* __restrict__ outb, float* __restrict__ outf)
{
  __shared__ u16 lA[128 * 32];
  __shared__ u16 lB[128 * 32];
  int bid = (int)blockIdx.x;
  bid = (bid & 7) * NB + (bid >> 3);       // XCD-contiguous row bands (grid%8==0)
  const int row0 = (bid >> 3) * 128;
  const int col0 = (bid & 7) * 128;
  const int t = threadIdx.x;
  const int w = t >> 6, lane = t & 63;
  const int l15 = lane & 15, l4 = lane >> 4;
  const int wr = w >> 1, wc = w & 1;

  const int c0 = t, c1 = 256 + t;
  const u16* gA0 = A + (row0 + (c0 >> 2)) * 1024 + (c0 & 3) * 8;
  const u16* gA1 = A + (row0 + (c1 >> 2)) * 1024 + (c1 & 3) * 8;
  const u16* gB0 = Bt + (col0 + (c0 >> 2)) * 1024 + (c0 & 3) * 8;
  const u16* gB1 = Bt + (col0 + (c1 >> 2)) * 1024 + (c1 & 3) * 8;
  u16* lA0 = lA + (w * 64) * 8;
  u16* lA1 = lA + (256 + w * 64) * 8;
  u16* lB0 = lB + (w * 64) * 8;
  u16* lB1 = lB + (256 + w * 64) * 8;

  f32x4 acc[4][4] = {};

  for (int kt = 0; kt < 1024; kt += 32) {
    gld16(gA0 + kt, lA0);
    gld16(gA1 + kt, lA1);
    gld16(gB0 + kt, lB0);
    gld16(gB1 + kt, lB1);
    __syncthreads();
    bf16x8 aF[4], bF[4];
#pragma unroll
    for (int m = 0; m < 4; ++m)
      aF[m] = *reinterpret_cast<const bf16x8*>(&lA[(wr * 64 + m * 16 + l15) * 32 + l4 * 8]);
#pragma unroll
    for (int n = 0; n < 4; ++n)
      bF[n] = *reinterpret_cast<const bf16x8*>(&lB[(wc * 64 + n * 16 + l15) * 32 + l4 * 8]);
#pragma unroll
    for (int m = 0; m < 4; ++m)
#pragma unroll
      for (int n = 0; n < 4; ++n)
        acc[m][n] = __builtin_amdgcn_mfma_f32_16x16x32_bf16(aF[m], bF[n], acc[m][n], 0, 0, 0);
    __syncthreads();
  }

  float bv[4];
#pragma unroll
  for (int n = 0; n < 4; ++n)
    bv[n] = (EPI == 4) ? 0.0f : bias[col0 + wc * 64 + n * 16 + l15];
#pragma unroll
  for (int m = 0; m < 4; ++m) {
#pragma unroll
    for (int n = 0; n < 4; ++n) {
      const int c = col0 + wc * 64 + n * 16 + l15;
#pragma unroll
      for (int j = 0; j < 4; ++j) {
        const int r = row0 + wr * 64 + m * 16 + l4 * 4 + j;
        const float v = acc[m][n][j] + bv[n];
        if constexpr (EPI == 0 || EPI == 4) {
          outb[r * 1024 + c] = f2bf(v);
        } else if constexpr (EPI == 1) {
          outf[r * 1024 + c] = v;
          outb[r * 1024 + c] = f2bf(v);
        } else if constexpr (EPI == 2) {
          const int bi = r >> 10, s = r & 1023;
          const int h = c >> 6, d = c & 63;
          outb[((bi * 16 + h) * 64 + d) * 1024 + s] = f2bf(v);
        } else {
          outf[r * 1024 + c] = v;
        }
      }
    }
  }
}

// ---------------- flash attention v5: swapped-QK^T, in-register softmax -------
// 32x32x16 MFMAs. S^T = mfma(K,Q): lane holds 16 scores of tile for q=lane&31,
// kv = (r&3)+8*(r>>2)+4*(lane>>5). Softmax lane-local; P packed to bf16 via
// v_cvt_pk_bf16_f32 + shfl_xor(32) half-exchange -> PV A-operand from regs.
// Wave-uniform running max + T13 defer-rescale (THR=8). K/V LDS staging,
// T14 async-stage, XCD co-location as v4.
__global__ __launch_bounds__(256, 3)
void attn_k(const u16* __restrict__ Q, const u16* __restrict__ K,
            const u16* __restrict__ Vt, u16* __restrict__ ctx)
{
  __shared__ u16 lK[64 * 72];
  __shared__ u16 lV[64 * 72];
  __shared__ float lsumI[4][32];
  const int id = (int)blockIdx.x;
  const int xcd = id & 7, o = id >> 3;
  const int pair = xcd * 16 + (o >> 3);   // 16 (b,h) pairs per XCD
  const int qt = o & 7;
  const int b = pair >> 4, h = pair & 15;
  const int t = threadIdx.x, w = t >> 6, lane = t & 63;
  const int l31 = lane & 31, hi = lane >> 5;
  const int q0 = qt * 128 + w * 32;
  const u16* Qp = Q + (size_t)b * (1024 * 1024) + h * 64;
  const u16* Kp = K + (size_t)b * (1024 * 1024) + h * 64;
  const u16* Vp = Vt + (size_t)(b * 16 + h) * (64 * 1024);

  // staging slots: thread t owns rows r0 and r0+32, 16B chunk c0 (u16 units)
  const int r0 = t >> 3, c0 = (t & 7) * 8;

  // Q fragments (B-operand: lane holds Q[q=l31][d = ks*16 + hi*8 + i])
  bf16x8 bQ[4];
#pragma unroll
  for (int ks = 0; ks < 4; ++ks)
    bQ[ks] = *reinterpret_cast<const bf16x8*>(&Qp[(q0 + l31) * 1024 + ks * 16 + hi * 8]);

  f32x16 acc[2] = {};
  float lsum = 0.f;
  float m_run = -3.0e38f;

  // prologue: issue tile-0 loads
  bf16x8 sK0, sK1, sV0, sV1;
  sK0 = *reinterpret_cast<const bf16x8*>(&Kp[(r0) * 1024 + c0]);
  sK1 = *reinterpret_cast<const bf16x8*>(&Kp[(r0 + 32) * 1024 + c0]);
  sV0 = *reinterpret_cast<const bf16x8*>(&Vp[r0 * 1024 + c0]);
  sV1 = *reinterpret_cast<const bf16x8*>(&Vp[(r0 + 32) * 1024 + c0]);

  for (int it = 0; it < 16; ++it) {
    const int kv0 = it * 64;
    __syncthreads();   // all waves done reading previous tile
    *reinterpret_cast<bf16x8*>(&lK[r0 * 72 + c0]) = sK0;
    *reinterpret_cast<bf16x8*>(&lK[(r0 + 32) * 72 + c0]) = sK1;
    *reinterpret_cast<bf16x8*>(&lV[r0 * 72 + c0]) = sV0;
    *reinterpret_cast<bf16x8*>(&lV[(r0 + 32) * 72 + c0]) = sV1;
    __syncthreads();   // tile ready
    if (it + 1 < 16) {  // issue next tile: in flight during the whole compute
      const int nk = kv0 + 64;
      sK0 = *reinterpret_cast<const bf16x8*>(&Kp[(nk + r0) * 1024 + c0]);
      sK1 = *reinterpret_cast<const bf16x8*>(&Kp[(nk + r0 + 32) * 1024 + c0]);
      sV0 = *reinterpret_cast<const bf16x8*>(&Vp[r0 * 1024 + nk + c0]);
      sV1 = *reinterpret_cast<const bf16x8*>(&Vp[(r0 + 32) * 1024 + nk + c0]);
    }

    // S^T = K Q^T: rows=kv (regs), cols=q (lanes). 2 kv-tiles of 32.
    f32x16 sS[2] = {};
    __builtin_amdgcn_s_setprio(1);
#pragma unroll
    for (int tt = 0; tt < 2; ++tt) {
#pragma unroll
      for (int ks = 0; ks < 4; ++ks) {
        const bf16x8 aK = *reinterpret_cast<const bf16x8*>(
            &lK[(tt * 32 + l31) * 72 + ks * 16 + hi * 8]);
        sS[tt] = __builtin_amdgcn_mfma_f32_32x32x16_bf16(aK, bQ[ks], sS[tt], 0, 0, 0);
      }
    }
    __builtin_amdgcn_s_setprio(0);

    // wave-uniform tile max
    float tm = sS[0][0];
#pragma unroll
    for (int r = 1; r < 16; ++r) tm = fmaxf(tm, sS[0][r]);
#pragma unroll
    for (int r = 0; r < 16; ++r) tm = fmaxf(tm, sS[1][r]);
#pragma unroll
    for (int d = 1; d < 64; d <<= 1) tm = fmaxf(tm, __shfl_xor(tm, d));
    const float nm = fmaxf(m_run, tm);
    if (nm - m_run > 8.0f) {   // T13 defer-rescale (uniform branch)
      const float psc = __builtin_amdgcn_exp2f(m_run - nm);
#pragma unroll
      for (int dt = 0; dt < 2; ++dt)
#pragma unroll
        for (int r = 0; r < 16; ++r) acc[dt][r] *= psc;
      lsum *= psc;
      m_run = nm;
    }

    // P = exp2(S - m_run); pack to bf16 pairs; half-exchange -> PV A-frags
    unsigned pa[2][2][4];
#pragma unroll
    for (int tt = 0; tt < 2; ++tt) {
      float p[16];
#pragma unroll
      for (int r = 0; r < 16; ++r) {
        p[r] = __builtin_amdgcn_exp2f(sS[tt][r] - m_run);
        lsum += p[r];
      }
      unsigned wv[8];
#pragma unroll
      for (int i = 0; i < 8; ++i) wv[i] = cvtpk(p[2 * i], p[2 * i + 1]);
#pragma unroll
      for (int c = 0; c < 2; ++c) {
        const unsigned pw0 = (unsigned)__shfl_xor((int)wv[4 * c + 0], 32);
        const unsigned pw1 = (unsigned)__shfl_xor((int)wv[4 * c + 1], 32);
        const unsigned pw2 = (unsigned)__shfl_xor((int)wv[4 * c + 2], 32);
        const unsigned pw3 = (unsigned)__shfl_xor((int)wv[4 * c + 3], 32);
        pa[tt][c][0] = hi ? pw2 : wv[4 * c + 0];
        pa[tt][c][1] = hi ? pw3 : wv[4 * c + 1];
        pa[tt][c][2] = hi ? wv[4 * c + 2] : pw0;
        pa[tt][c][3] = hi ? wv[4 * c + 3] : pw1;
      }
    }

    // ctx += P @ V : A = P (rows=q), B = V^T rows (=d) from lV
    __builtin_amdgcn_s_setprio(1);
#pragma unroll
    for (int tt = 0; tt < 2; ++tt)
#pragma unroll
      for (int c = 0; c < 2; ++c) {
        u32x4v pw;
        pw.x = pa[tt][c][0]; pw.y = pa[tt][c][1];
        pw.z = pa[tt][c][2]; pw.w = pa[tt][c][3];
        const bf16x8 aP = __builtin_bit_cast(bf16x8, pw);
#pragma unroll
        for (int dt = 0; dt < 2; ++dt) {
          const bf16x8 bV = *reinterpret_cast<const bf16x8*>(
              &lV[(dt * 32 + l31) * 72 + tt * 32 + c * 16 + hi * 8]);
          acc[dt] = __builtin_amdgcn_mfma_f32_32x32x16_bf16(aP, bV, acc[dt], 0, 0, 0);
        }
      }
    __builtin_amdgcn_s_setprio(0);
  }

  // combine half-wave partial sums; broadcast inverse via per-wave LDS
  const float ltot = lsum + __shfl_xor(lsum, 32);
  if (hi == 0) lsumI[w][l31] = 1.0f / ltot;
  u16* Cp = ctx + (size_t)b * (1024 * 1024) + h * 64;
#pragma unroll
  for (int dt = 0; dt < 2; ++dt)
#pragma unroll
    for (int r = 0; r < 16; ++r) {
      const int q = (r & 3) + 8 * (r >> 2) + 4 * hi;
      const float inv = lsumI[w][q];
      Cp[(q0 + q) * 1024 + dt * 32 + l31] = f2bf(acc[dt][r] * inv);
    }
}

// ---------------- driver ------------------------------------------------------
extern "C" void kernel_launch(void* const* d_in, const int* in_sizes, int n_in,
                              void* d_out, int out_size, void* d_ws, size_t ws_size,
                              hipStream_t stream)
{
  (void)in_sizes; (void)n_in; (void)out_size; (void)ws_size;
  const float* X  = (const float*)d_in[0];
  const float* Y  = (const float*)d_in[1];
  const float* Wq = (const float*)d_in[2];
  const float* bq = (const float*)d_in[3];
  const float* Wk = (const float*)d_in[4];
  const float* bk = (const float*)d_in[5];
  const float* Wv = (const float*)d_in[6];
  const float* bv = (const float*)d_in[7];
  const float* Wg = (const float*)d_in[8];
  const float* bg = (const float*)d_in[9];
  const float* Wb = (const float*)d_in[10];
  const float* bb = (const float*)d_in[11];
  const float* Wo = (const float*)d_in[12];
  const float* bo = (const float*)d_in[13];
  float* out = (float*)d_out;
  char* ws = (char*)d_ws;
  const size_t MB = 1024ull * 1024ull;

  u16* Wqt = (u16*)(ws + 0 * MB);
  u16* Wkt = (u16*)(ws + 2 * MB);
  u16* Wvt = (u16*)(ws + 4 * MB);
  u16* Wcn = (u16*)(ws + 6 * MB);    // Wc = 8*Wg+Wb, non-transposed bf16
  u16* Wot = (u16*)(ws + 8 * MB);
  u16* Wcot = (u16*)(ws + 10 * MB);  // (Wc @ Wo)^T bf16
  u16* Xb = (u16*)(ws + 12 * MB);
  u16* Yb = (u16*)(ws + 28 * MB);   // original Y bf16; later reused for Y_new bf16
  u16* Qb = (u16*)(ws + 44 * MB);
  u16* Kb = (u16*)(ws + 60 * MB);
  u16* Vt = (u16*)(ws + 76 * MB);
  u16* Cx = (u16*)(ws + 92 * MB);
  float* bqs = (float*)(ws + 108 * MB);
  float* bcs = (float*)(ws + 108 * MB + 4096);
  float* bco = (float*)(ws + 108 * MB + 8192);
  const int NEL = 8 * 1024 * 1024;

  prep_w<<<dim3(32, 32, 5), dim3(32, 8), 0, stream>>>(Wq, Wk, Wv, Wg, Wb, Wo,
                                                      Wqt, Wkt, Wvt, Wcn, Wot);
  prep_b<<<4, 256, 0, stream>>>(bq, bg, bb, bqs, bcs);
  fuse_bias<<<4, 256, 0, stream>>>(bcs, Wo, bo, bco);
  // Wcot[r][c] = sum_k Wot[r][k]*Wcn[c][k] = (Wc@Wo)^T, no bias
  gemm_k<4, 8><<<64, 256, 0, stream>>>(Wot, Wcn, nullptr, Wcot, nullptr);
  cvt_bf16<<<2048, 256, 0, stream>>>(X, Xb, NEL);
  cvt_bf16<<<2048, 256, 0, stream>>>(Y, Yb, NEL);

  // pass 1: queries from X, kv from Y  -> Y_new
  gemm_k<0><<<512, 256, 0, stream>>>(Xb, Wqt, bqs, Qb, nullptr);
  gemm_k<0><<<512, 256, 0, stream>>>(Yb, Wkt, bk, Kb, nullptr);
  gemm_k<2><<<512, 256, 0, stream>>>(Yb, Wvt, bv, Vt, nullptr);
  attn_k<<<dim3(1024), 256, 0, stream>>>(Qb, Kb, Vt, Cx);
  gemm_k<1><<<512, 256, 0, stream>>>(Cx, Wcot, bco, Yb, out + NEL);   // Y_new (f32+bf16)

  // pass 2: queries from Y_new, kv from X -> X_new
  gemm_k<0><<<512, 256, 0, stream>>>(Yb, Wqt, bqs, Qb, nullptr);
  gemm_k<0><<<512, 256, 0, stream>>>(Xb, Wkt, bk, Kb, nullptr);
  gemm_k<2><<<512, 256, 0, stream>>>(Xb, Wvt, bv, Vt, nullptr);
  attn_k<<<dim3(1024), 256, 0, stream>>>(Qb, Kb, Vt, Cx);
  gemm_k<3><<<512, 256, 0, stream>>>(Cx, Wcot, bco, nullptr, out);    // X_new (f32)
}

// Round 8
// 350.621 us; speedup vs baseline: 1.8193x; 1.2029x over previous
//
#include <hip/hip_runtime.h>

typedef unsigned short u16;
typedef __bf16 bf16x8 __attribute__((ext_vector_type(8)));
typedef float f32x4 __attribute__((ext_vector_type(4)));
typedef float f32x16 __attribute__((ext_vector_type(16)));
typedef u16 u16x4 __attribute__((ext_vector_type(4)));
typedef unsigned int u32x4v __attribute__((ext_vector_type(4)));

#define LOG2E_OVER_8 0.18033688011112043f

__device__ __forceinline__ u16 f2bf(float f) {
  union { float f; unsigned int u; } x{f};
  unsigned int r = (x.u + 0x7fffu + ((x.u >> 16) & 1u)) >> 16;
  return (u16)r;
}

__device__ __forceinline__ float bf2f(u16 v) {
  union { unsigned int u; float f; } x;
  x.u = ((unsigned int)v) << 16;
  return x.f;
}

__device__ __forceinline__ unsigned cvtpk(float a, float b) {
  unsigned r;
  asm("v_cvt_pk_bf16_f32 %0, %1, %2" : "=v"(r) : "v"(a), "v"(b));
  return r;
}

__device__ __forceinline__ void gld16(const void* g, void* l) {
  __builtin_amdgcn_global_load_lds((const __attribute__((address_space(1))) unsigned int*)g,
                                   (__attribute__((address_space(3))) unsigned int*)l,
                                   16, 0, 0);
}

// ---------------- weight prep -------------------------------------------------
// m=0: Wqt = (Wq*log2e/8)^T   m=1: Wkt = Wk^T   m=2: Wvt = Wv^T
// m=3: Wcn = 8*Wg + Wbeta, NON-transposed bf16   m=4: Wot = Wo^T
__global__ void prep_w(const float* __restrict__ Wq, const float* __restrict__ Wk,
                       const float* __restrict__ Wv, const float* __restrict__ Wg,
                       const float* __restrict__ Wb, const float* __restrict__ Wo,
                       u16* __restrict__ Wqt, u16* __restrict__ Wkt, u16* __restrict__ Wvt,
                       u16* __restrict__ Wcn, u16* __restrict__ Wot)
{
  __shared__ float tile[32][33];
  const int m = blockIdx.z;
  const int nb = blockIdx.x * 32, kb = blockIdx.y * 32;
  const int tx = threadIdx.x, ty = threadIdx.y;
  const float* src = (m == 0) ? Wq : (m == 1) ? Wk : (m == 2) ? Wv : (m == 3) ? Wg : Wo;
  u16* dst = (m == 0) ? Wqt : (m == 1) ? Wkt : (m == 2) ? Wvt : (m == 3) ? Wcn : Wot;
#pragma unroll
  for (int i = 0; i < 4; ++i) {
    const int k = kb + ty + i * 8;
    float v = src[k * 1024 + nb + tx];
    if (m == 3) v = 8.0f * v + Wb[k * 1024 + nb + tx];
    if (m == 0) v *= LOG2E_OVER_8;
    if (m == 3) dst[k * 1024 + nb + tx] = f2bf(v);   // direct, non-transposed
    else        tile[ty + i * 8][tx] = v;
  }
  __syncthreads();
  if (m != 3) {
#pragma unroll
    for (int i = 0; i < 4; ++i) {
      const int r = ty + i * 8;
      dst[(nb + r) * 1024 + kb + tx] = f2bf(tile[tx][r]);
    }
  }
}

__global__ void prep_b(const float* __restrict__ bq, const float* __restrict__ bg,
                       const float* __restrict__ bb,
                       float* __restrict__ bqs, float* __restrict__ bcs)
{
  const int i = blockIdx.x * 256 + threadIdx.x;
  if (i < 1024) {
    bqs[i] = bq[i] * LOG2E_OVER_8;
    bcs[i] = 8.0f * bg[i] + bb[i];
  }
}

// bco[n] = dot(bcs, Wot-row-n) + bo[n]; 1024 blocks x 256 threads, coalesced
__global__ void bias_dot(const float* __restrict__ bcs, const u16* __restrict__ Wot,
                         const float* __restrict__ bo, float* __restrict__ bco)
{
  __shared__ float part[4];
  const int n = blockIdx.x, t = threadIdx.x;
  const u16* row = Wot + n * 1024;
  float a = 0.f;
#pragma unroll
  for (int i = 0; i < 4; ++i) {
    const int m = t + i * 256;
    a += bcs[m] * bf2f(row[m]);
  }
#pragma unroll
  for (int d = 1; d < 64; d <<= 1) a += __shfl_xor(a, d);
  if ((t & 63) == 0) part[t >> 6] = a;
  __syncthreads();
  if (t == 0) bco[n] = part[0] + part[1] + part[2] + part[3] + bo[n];
}

// ---------------- f32 -> bf16 convert ----------------------------------------
__global__ void cvt_bf16(const float* __restrict__ in, u16* __restrict__ out, int n)
{
  int i = (blockIdx.x * blockDim.x + threadIdx.x) * 4;
  const int stride = gridDim.x * blockDim.x * 4;
  for (; i < n; i += stride) {
    const float4 v = *reinterpret_cast<const float4*>(in + i);
    u16x4 o;
    o.x = f2bf(v.x); o.y = f2bf(v.y); o.z = f2bf(v.z); o.w = f2bf(v.w);
    *reinterpret_cast<u16x4*>(out + i) = o;
  }
}

// ---------------- GEMM body: C[NB*128 x 1024] = A @ Bt^T + bias ---------------
// EPI: 0 = bf16 out; 1 = fp32 + bf16 out; 2 = bf16 out transposed per head
//      Vt[b][h][d][s]; 3 = fp32 out only; 4 = bf16 out, NO bias.
template<int EPI, int NB>
__device__ __forceinline__ void gemm_body(int bid0, u16* lA, u16* lB,
                                          const u16* __restrict__ A,
                                          const u16* __restrict__ Bt,
                                          const float* __restrict__ bias,
                                          u16* __restrict__ outb, float* __restrict__ outf)
{
  int bid = (bid0 & 7) * NB + (bid0 >> 3);   // XCD-contiguous row bands (grid%8==0)
  const int row0 = (bid >> 3) * 128;
  const int col0 = (bid & 7) * 128;
  const int t = threadIdx.x;
  const int w = t >> 6, lane = t & 63;
  const int l15 = lane & 15, l4 = lane >> 4;
  const int wr = w >> 1, wc = w & 1;

  const int c0 = t, c1 = 256 + t;
  const u16* gA0 = A + (row0 + (c0 >> 2)) * 1024 + (c0 & 3) * 8;
  const u16* gA1 = A + (row0 + (c1 >> 2)) * 1024 + (c1 & 3) * 8;
  const u16* gB0 = Bt + (col0 + (c0 >> 2)) * 1024 + (c0 & 3) * 8;
  const u16* gB1 = Bt + (col0 + (c1 >> 2)) * 1024 + (c1 & 3) * 8;
  u16* lA0 = lA + (w * 64) * 8;
  u16* lA1 = lA + (256 + w * 64) * 8;
  u16* lB0 = lB + (w * 64) * 8;
  u16* lB1 = lB + (256 + w * 64) * 8;

  f32x4 acc[4][4] = {};

  for (int kt = 0; kt < 1024; kt += 32) {
    gld16(gA0 + kt, lA0);
    gld16(gA1 + kt, lA1);
    gld16(gB0 + kt, lB0);
    gld16(gB1 + kt, lB1);
    __syncthreads();
    bf16x8 aF[4], bF[4];
#pragma unroll
    for (int m = 0; m < 4; ++m)
      aF[m] = *reinterpret_cast<const bf16x8*>(&lA[(wr * 64 + m * 16 + l15) * 32 + l4 * 8]);
#pragma unroll
    for (int n = 0; n < 4; ++n)
      bF[n] = *reinterpret_cast<const bf16x8*>(&lB[(wc * 64 + n * 16 + l15) * 32 + l4 * 8]);
#pragma unroll
    for (int m = 0; m < 4; ++m)
#pragma unroll
      for (int n = 0; n < 4; ++n)
        acc[m][n] = __builtin_amdgcn_mfma_f32_16x16x32_bf16(aF[m], bF[n], acc[m][n], 0, 0, 0);
    __syncthreads();
  }

  float bv[4];
#pragma unroll
  for (int n = 0; n < 4; ++n)
    bv[n] = (EPI == 4) ? 0.0f : bias[col0 + wc * 64 + n * 16 + l15];
#pragma unroll
  for (int m = 0; m < 4; ++m) {
#pragma unroll
    for (int n = 0; n < 4; ++n) {
      const int c = col0 + wc * 64 + n * 16 + l15;
#pragma unroll
      for (int j = 0; j < 4; ++j) {
        const int r = row0 + wr * 64 + m * 16 + l4 * 4 + j;
        const float v = acc[m][n][j] + bv[n];
        if constexpr (EPI == 0 || EPI == 4) {
          outb[r * 1024 + c] = f2bf(v);
        } else if constexpr (EPI == 1) {
          outf[r * 1024 + c] = v;
          outb[r * 1024 + c] = f2bf(v);
        } else if constexpr (EPI == 2) {
          const int bi = r >> 10, s = r & 1023;
          const int h = c >> 6, d = c & 63;
          outb[((bi * 16 + h) * 64 + d) * 1024 + s] = f2bf(v);
        } else {
          outf[r * 1024 + c] = v;
        }
      }
    }
  }
}

template<int EPI, int NB = 64>
__global__ __launch_bounds__(256, 3)
void gemm_k(const u16* __restrict__ A, const u16* __restrict__ Bt,
            const float* __restrict__ bias,
            u16* __restrict__ outb, float* __restrict__ outf)
{
  __shared__ u16 lA[128 * 32];
  __shared__ u16 lB[128 * 32];
  gemm_body<EPI, NB>((int)blockIdx.x, lA, lB, A, Bt, bias, outb, outf);
}

// merged Q/K/V: jobs 0,1 -> EPI 0; job 2 -> EPI 2 (Vt). 1536 blocks.
__global__ __launch_bounds__(256, 3)
void gemm3_k(const u16* __restrict__ A0, const u16* __restrict__ B0,
             const float* __restrict__ c0, u16* __restrict__ o0,
             const u16* __restrict__ A1, const u16* __restrict__ B1,
             const float* __restrict__ c1, u16* __restrict__ o1,
             const u16* __restrict__ A2, const u16* __restrict__ B2,
             const float* __restrict__ c2, u16* __restrict__ o2)
{
  __shared__ u16 lA[128 * 32];
  __shared__ u16 lB[128 * 32];
  const int id = (int)blockIdx.x;
  if (id < 512)       gemm_body<0, 64>(id,        lA, lB, A0, B0, c0, o0, nullptr);
  else if (id < 1024) gemm_body<0, 64>(id - 512,  lA, lB, A1, B1, c1, o1, nullptr);
  else                gemm_body<2, 64>(id - 1024, lA, lB, A2, B2, c2, o2, nullptr);
}

// ---------------- flash attention v5: swapped-QK^T, in-register softmax -------
// 32x32x16 MFMAs. S^T = mfma(K,Q): lane holds 16 scores of tile for q=lane&31,
// kv = (r&3)+8*(r>>2)+4*(lane>>5). Softmax lane-local; P packed to bf16 via
// v_cvt_pk_bf16_f32 + shfl_xor(32) half-exchange -> PV A-operand from regs.
// Wave-uniform running max + T13 defer-rescale (THR=8). K/V LDS staging,
// T14 async-stage, XCD co-location. (256,4): 4 blocks/CU (grid=1024=4/CU).
__global__ __launch_bounds__(256, 4)
void attn_k(const u16* __restrict__ Q, const u16* __restrict__ K,
            const u16* __restrict__ Vt, const u16* __restrict__ ctx_unused,
            u16* __restrict__ ctx)
{
  __shared__ u16 lK[64 * 72];
  __shared__ u16 lV[64 * 72];
  __shared__ float lsumI[4][32];
  const int id = (int)blockIdx.x;
  const int xcd = id & 7, o = id >> 3;
  const int pair = xcd * 16 + (o >> 3);   // 16 (b,h) pairs per XCD
  const int qt = o & 7;
  const int b = pair >> 4, h = pair & 15;
  const int t = threadIdx.x, w = t >> 6, lane = t & 63;
  const int l31 = lane & 31, hi = lane >> 5;
  const int q0 = qt * 128 + w * 32;
  const u16* Qp = Q + (size_t)b * (1024 * 1024) + h * 64;
  const u16* Kp = K + (size_t)b * (1024 * 1024) + h * 64;
  const u16* Vp = Vt + (size_t)(b * 16 + h) * (64 * 1024);

  // staging slots: thread t owns rows r0 and r0+32, 16B chunk c0 (u16 units)
  const int r0 = t >> 3, c0 = (t & 7) * 8;

  // Q fragments (B-operand: lane holds Q[q=l31][d = ks*16 + hi*8 + i])
  bf16x8 bQ[4];
#pragma unroll
  for (int ks = 0; ks < 4; ++ks)
    bQ[ks] = *reinterpret_cast<const bf16x8*>(&Qp[(q0 + l31) * 1024 + ks * 16 + hi * 8]);

  f32x16 acc[2] = {};
  float lsum = 0.f;
  float m_run = -3.0e38f;

  // prologue: issue tile-0 loads
  bf16x8 sK0, sK1, sV0, sV1;
  sK0 = *reinterpret_cast<const bf16x8*>(&Kp[(r0) * 1024 + c0]);
  sK1 = *reinterpret_cast<const bf16x8*>(&Kp[(r0 + 32) * 1024 + c0]);
  sV0 = *reinterpret_cast<const bf16x8*>(&Vp[r0 * 1024 + c0]);
  sV1 = *reinterpret_cast<const bf16x8*>(&Vp[(r0 + 32) * 1024 + c0]);

  for (int it = 0; it < 16; ++it) {
    const int kv0 = it * 64;
    __syncthreads();   // all waves done reading previous tile
    *reinterpret_cast<bf16x8*>(&lK[r0 * 72 + c0]) = sK0;
    *reinterpret_cast<bf16x8*>(&lK[(r0 + 32) * 72 + c0]) = sK1;
    *reinterpret_cast<bf16x8*>(&lV[r0 * 72 + c0]) = sV0;
    *reinterpret_cast<bf16x8*>(&lV[(r0 + 32) * 72 + c0]) = sV1;
    __syncthreads();   // tile ready
    if (it + 1 < 16) {  // issue next tile: in flight during the whole compute
      const int nk = kv0 + 64;
      sK0 = *reinterpret_cast<const bf16x8*>(&Kp[(nk + r0) * 1024 + c0]);
      sK1 = *reinterpret_cast<const bf16x8*>(&Kp[(nk + r0 + 32) * 1024 + c0]);
      sV0 = *reinterpret_cast<const bf16x8*>(&Vp[r0 * 1024 + nk + c0]);
      sV1 = *reinterpret_cast<const bf16x8*>(&Vp[(r0 + 32) * 1024 + nk + c0]);
    }

    // S^T = K Q^T: rows=kv (regs), cols=q (lanes). 2 kv-tiles of 32.
    f32x16 sS[2] = {};
    __builtin_amdgcn_s_setprio(1);
#pragma unroll
    for (int tt = 0; tt < 2; ++tt) {
#pragma unroll
      for (int ks = 0; ks < 4; ++ks) {
        const bf16x8 aK = *reinterpret_cast<const bf16x8*>(
            &lK[(tt * 32 + l31) * 72 + ks * 16 + hi * 8]);
        sS[tt] = __builtin_amdgcn_mfma_f32_32x32x16_bf16(aK, bQ[ks], sS[tt], 0, 0, 0);
      }
    }
    __builtin_amdgcn_s_setprio(0);

    // wave-uniform tile max
    float tm = sS[0][0];
#pragma unroll
    for (int r = 1; r < 16; ++r) tm = fmaxf(tm, sS[0][r]);
#pragma unroll
    for (int r = 0; r < 16; ++r) tm = fmaxf(tm, sS[1][r]);
#pragma unroll
    for (int d = 1; d < 64; d <<= 1) tm = fmaxf(tm, __shfl_xor(tm, d));
    const float nm = fmaxf(m_run, tm);
    if (nm - m_run > 8.0f) {   // T13 defer-rescale (uniform branch)
      const float psc = __builtin_amdgcn_exp2f(m_run - nm);
#pragma unroll
      for (int dt = 0; dt < 2; ++dt)
#pragma unroll
        for (int r = 0; r < 16; ++r) acc[dt][r] *= psc;
      lsum *= psc;
      m_run = nm;
    }

    // P = exp2(S - m_run); pack to bf16 pairs; half-exchange -> PV A-frags
    unsigned pa[2][2][4];
#pragma unroll
    for (int tt = 0; tt < 2; ++tt) {
      float p[16];
#pragma unroll
      for (int r = 0; r < 16; ++r) {
        p[r] = __builtin_amdgcn_exp2f(sS[tt][r] - m_run);
        lsum += p[r];
      }
      unsigned wv[8];
#pragma unroll
      for (int i = 0; i < 8; ++i) wv[i] = cvtpk(p[2 * i], p[2 * i + 1]);
#pragma unroll
      for (int c = 0; c < 2; ++c) {
        const unsigned pw0 = (unsigned)__shfl_xor((int)wv[4 * c + 0], 32);
        const unsigned pw1 = (unsigned)__shfl_xor((int)wv[4 * c + 1], 32);
        const unsigned pw2 = (unsigned)__shfl_xor((int)wv[4 * c + 2], 32);
        const unsigned pw3 = (unsigned)__shfl_xor((int)wv[4 * c + 3], 32);
        pa[tt][c][0] = hi ? pw2 : wv[4 * c + 0];
        pa[tt][c][1] = hi ? pw3 : wv[4 * c + 1];
        pa[tt][c][2] = hi ? wv[4 * c + 2] : pw0;
        pa[tt][c][3] = hi ? wv[4 * c + 3] : pw1;
      }
    }

    // ctx += P @ V : A = P (rows=q), B = V^T rows (=d) from lV
    __builtin_amdgcn_s_setprio(1);
#pragma unroll
    for (int tt = 0; tt < 2; ++tt)
#pragma unroll
      for (int c = 0; c < 2; ++c) {
        u32x4v pw;
        pw.x = pa[tt][c][0]; pw.y = pa[tt][c][1];
        pw.z = pa[tt][c][2]; pw.w = pa[tt][c][3];
        const bf16x8 aP = __builtin_bit_cast(bf16x8, pw);
#pragma unroll
        for (int dt = 0; dt < 2; ++dt) {
          const bf16x8 bV = *reinterpret_cast<const bf16x8*>(
              &lV[(dt * 32 + l31) * 72 + tt * 32 + c * 16 + hi * 8]);
          acc[dt] = __builtin_amdgcn_mfma_f32_32x32x16_bf16(aP, bV, acc[dt], 0, 0, 0);
        }
      }
    __builtin_amdgcn_s_setprio(0);
  }

  // combine half-wave partial sums; broadcast inverse via per-wave LDS
  const float ltot = lsum + __shfl_xor(lsum, 32);
  if (hi == 0) lsumI[w][l31] = 1.0f / ltot;
  u16* Cp = ctx + (size_t)b * (1024 * 1024) + h * 64;
#pragma unroll
  for (int dt = 0; dt < 2; ++dt)
#pragma unroll
    for (int r = 0; r < 16; ++r) {
      const int q = (r & 3) + 8 * (r >> 2) + 4 * hi;
      const float inv = lsumI[w][q];
      Cp[(q0 + q) * 1024 + dt * 32 + l31] = f2bf(acc[dt][r] * inv);
    }
}

// ---------------- driver ------------------------------------------------------
extern "C" void kernel_launch(void* const* d_in, const int* in_sizes, int n_in,
                              void* d_out, int out_size, void* d_ws, size_t ws_size,
                              hipStream_t stream)
{
  (void)in_sizes; (void)n_in; (void)out_size; (void)ws_size;
  const float* X  = (const float*)d_in[0];
  const float* Y  = (const float*)d_in[1];
  const float* Wq = (const float*)d_in[2];
  const float* bq = (const float*)d_in[3];
  const float* Wk = (const float*)d_in[4];
  const float* bk = (const float*)d_in[5];
  const float* Wv = (const float*)d_in[6];
  const float* bv = (const float*)d_in[7];
  const float* Wg = (const float*)d_in[8];
  const float* bg = (const float*)d_in[9];
  const float* Wb = (const float*)d_in[10];
  const float* bb = (const float*)d_in[11];
  const float* Wo = (const float*)d_in[12];
  const float* bo = (const float*)d_in[13];
  float* out = (float*)d_out;
  char* ws = (char*)d_ws;
  const size_t MB = 1024ull * 1024ull;

  u16* Wqt = (u16*)(ws + 0 * MB);
  u16* Wkt = (u16*)(ws + 2 * MB);
  u16* Wvt = (u16*)(ws + 4 * MB);
  u16* Wcn = (u16*)(ws + 6 * MB);    // Wc = 8*Wg+Wb, non-transposed bf16
  u16* Wot = (u16*)(ws + 8 * MB);
  u16* Wcot = (u16*)(ws + 10 * MB);  // (Wc @ Wo)^T bf16
  u16* Xb = (u16*)(ws + 12 * MB);
  u16* Yb = (u16*)(ws + 28 * MB);   // original Y bf16; later reused for Y_new bf16
  u16* Qb = (u16*)(ws + 44 * MB);
  u16* Kb = (u16*)(ws + 60 * MB);
  u16* Vt = (u16*)(ws + 76 * MB);
  u16* Cx = (u16*)(ws + 92 * MB);
  float* bqs = (float*)(ws + 108 * MB);
  float* bcs = (float*)(ws + 108 * MB + 4096);
  float* bco = (float*)(ws + 108 * MB + 8192);
  const int NEL = 8 * 1024 * 1024;

  prep_w<<<dim3(32, 32, 5), dim3(32, 8), 0, stream>>>(Wq, Wk, Wv, Wg, Wb, Wo,
                                                      Wqt, Wkt, Wvt, Wcn, Wot);
  prep_b<<<4, 256, 0, stream>>>(bq, bg, bb, bqs, bcs);
  bias_dot<<<1024, 256, 0, stream>>>(bcs, Wot, bo, bco);
  // Wcot[r][c] = sum_k Wot[r][k]*Wcn[c][k] = (Wc@Wo)^T, no bias
  gemm_k<4, 8><<<64, 256, 0, stream>>>(Wot, Wcn, nullptr, Wcot, nullptr);
  cvt_bf16<<<2048, 256, 0, stream>>>(X, Xb, NEL);
  cvt_bf16<<<2048, 256, 0, stream>>>(Y, Yb, NEL);

  // pass 1: queries from X, kv from Y  -> Y_new
  gemm3_k<<<1536, 256, 0, stream>>>(Xb, Wqt, bqs, Qb,
                                    Yb, Wkt, bk, Kb,
                                    Yb, Wvt, bv, Vt);
  attn_k<<<dim3(1024), 256, 0, stream>>>(Qb, Kb, Vt, nullptr, Cx);
  gemm_k<1><<<512, 256, 0, stream>>>(Cx, Wcot, bco, Yb, out + NEL);   // Y_new (f32+bf16)

  // pass 2: queries from Y_new, kv from X -> X_new
  gemm3_k<<<1536, 256, 0, stream>>>(Yb, Wqt, bqs, Qb,
                                    Xb, Wkt, bk, Kb,
                                    Xb, Wvt, bv, Vt);
  attn_k<<<dim3(1024), 256, 0, stream>>>(Qb, Kb, Vt, nullptr, Cx);
  gemm_k<3><<<512, 256, 0, stream>>>(Cx, Wcot, bco, nullptr, out);    // X_new (f32)
}

// Round 9
// 336.182 us; speedup vs baseline: 1.8974x; 1.0429x over previous
//
#include <hip/hip_runtime.h>

typedef unsigned short u16;
typedef __bf16 bf16x8 __attribute__((ext_vector_type(8)));
typedef float f32x4 __attribute__((ext_vector_type(4)));
typedef float f32x16 __attribute__((ext_vector_type(16)));
typedef u16 u16x4 __attribute__((ext_vector_type(4)));
typedef unsigned int u32x4v __attribute__((ext_vector_type(4)));

#define LOG2E_OVER_8 0.18033688011112043f

__device__ __forceinline__ u16 f2bf(float f) {
  union { float f; unsigned int u; } x{f};
  unsigned int r = (x.u + 0x7fffu + ((x.u >> 16) & 1u)) >> 16;
  return (u16)r;
}

__device__ __forceinline__ float bf2f(u16 v) {
  union { unsigned int u; float f; } x;
  x.u = ((unsigned int)v) << 16;
  return x.f;
}

__device__ __forceinline__ unsigned cvtpk(float a, float b) {
  unsigned r;
  asm("v_cvt_pk_bf16_f32 %0, %1, %2" : "=v"(r) : "v"(a), "v"(b));
  return r;
}

__device__ __forceinline__ void gld16(const void* g, void* l) {
  __builtin_amdgcn_global_load_lds((const __attribute__((address_space(1))) unsigned int*)g,
                                   (__attribute__((address_space(3))) unsigned int*)l,
                                   16, 0, 0);
}

// ---------------- weight prep -------------------------------------------------
// m=0: Wqt = (Wq*log2e/8)^T   m=1: Wkt = Wk^T   m=2: Wvt = Wv^T
// m=3: Wcn = 8*Wg + Wbeta, NON-transposed bf16   m=4: Wot = Wo^T
__global__ void prep_w(const float* __restrict__ Wq, const float* __restrict__ Wk,
                       const float* __restrict__ Wv, const float* __restrict__ Wg,
                       const float* __restrict__ Wb, const float* __restrict__ Wo,
                       u16* __restrict__ Wqt, u16* __restrict__ Wkt, u16* __restrict__ Wvt,
                       u16* __restrict__ Wcn, u16* __restrict__ Wot)
{
  __shared__ float tile[32][33];
  const int m = blockIdx.z;
  const int nb = blockIdx.x * 32, kb = blockIdx.y * 32;
  const int tx = threadIdx.x, ty = threadIdx.y;
  const float* src = (m == 0) ? Wq : (m == 1) ? Wk : (m == 2) ? Wv : (m == 3) ? Wg : Wo;
  u16* dst = (m == 0) ? Wqt : (m == 1) ? Wkt : (m == 2) ? Wvt : (m == 3) ? Wcn : Wot;
#pragma unroll
  for (int i = 0; i < 4; ++i) {
    const int k = kb + ty + i * 8;
    float v = src[k * 1024 + nb + tx];
    if (m == 3) v = 8.0f * v + Wb[k * 1024 + nb + tx];
    if (m == 0) v *= LOG2E_OVER_8;
    if (m == 3) dst[k * 1024 + nb + tx] = f2bf(v);   // direct, non-transposed
    else        tile[ty + i * 8][tx] = v;
  }
  __syncthreads();
  if (m != 3) {
#pragma unroll
    for (int i = 0; i < 4; ++i) {
      const int r = ty + i * 8;
      dst[(nb + r) * 1024 + kb + tx] = f2bf(tile[tx][r]);
    }
  }
}

__global__ void prep_b(const float* __restrict__ bq, const float* __restrict__ bg,
                       const float* __restrict__ bb,
                       float* __restrict__ bqs, float* __restrict__ bcs)
{
  const int i = blockIdx.x * 256 + threadIdx.x;
  if (i < 1024) {
    bqs[i] = bq[i] * LOG2E_OVER_8;
    bcs[i] = 8.0f * bg[i] + bb[i];
  }
}

// bco[n] = dot(bcs, Wot-row-n) + bo[n]; 1024 blocks x 256 threads, coalesced
__global__ void bias_dot(const float* __restrict__ bcs, const u16* __restrict__ Wot,
                         const float* __restrict__ bo, float* __restrict__ bco)
{
  __shared__ float part[4];
  const int n = blockIdx.x, t = threadIdx.x;
  const u16* row = Wot + n * 1024;
  float a = 0.f;
#pragma unroll
  for (int i = 0; i < 4; ++i) {
    const int m = t + i * 256;
    a += bcs[m] * bf2f(row[m]);
  }
#pragma unroll
  for (int d = 1; d < 64; d <<= 1) a += __shfl_xor(a, d);
  if ((t & 63) == 0) part[t >> 6] = a;
  __syncthreads();
  if (t == 0) bco[n] = part[0] + part[1] + part[2] + part[3] + bo[n];
}

// ---------------- f32 -> bf16 convert (both tensors, one dispatch) -----------
__global__ void cvt2_bf16(const float* __restrict__ in0, u16* __restrict__ out0,
                          const float* __restrict__ in1, u16* __restrict__ out1, int n)
{
  int i = (blockIdx.x * blockDim.x + threadIdx.x) * 4;
  const int stride = gridDim.x * blockDim.x * 4;
  for (; i < n; i += stride) {
    const float4 v0 = *reinterpret_cast<const float4*>(in0 + i);
    u16x4 o0;
    o0.x = f2bf(v0.x); o0.y = f2bf(v0.y); o0.z = f2bf(v0.z); o0.w = f2bf(v0.w);
    *reinterpret_cast<u16x4*>(out0 + i) = o0;
    const float4 v1 = *reinterpret_cast<const float4*>(in1 + i);
    u16x4 o1;
    o1.x = f2bf(v1.x); o1.y = f2bf(v1.y); o1.z = f2bf(v1.z); o1.w = f2bf(v1.w);
    *reinterpret_cast<u16x4*>(out1 + i) = o1;
  }
}

// ---------------- GEMM body: C[NB*128 x 1024] = A @ Bt^T + bias ---------------
// EPI: 0 = bf16 out; 1 = fp32 + bf16 out; 2 = bf16 out transposed per head
//      Vt[b][h][d][s]; 3 = fp32 out only; 4 = bf16 out, NO bias.
template<int EPI, int NB>
__device__ __forceinline__ void gemm_body(int bid0, u16* lA, u16* lB,
                                          const u16* __restrict__ A,
                                          const u16* __restrict__ Bt,
                                          const float* __restrict__ bias,
                                          u16* __restrict__ outb, float* __restrict__ outf)
{
  int bid = (bid0 & 7) * NB + (bid0 >> 3);   // XCD-contiguous row bands (grid%8==0)
  const int row0 = (bid >> 3) * 128;
  const int col0 = (bid & 7) * 128;
  const int t = threadIdx.x;
  const int w = t >> 6, lane = t & 63;
  const int l15 = lane & 15, l4 = lane >> 4;
  const int wr = w >> 1, wc = w & 1;

  const int c0 = t, c1 = 256 + t;
  const u16* gA0 = A + (row0 + (c0 >> 2)) * 1024 + (c0 & 3) * 8;
  const u16* gA1 = A + (row0 + (c1 >> 2)) * 1024 + (c1 & 3) * 8;
  const u16* gB0 = Bt + (col0 + (c0 >> 2)) * 1024 + (c0 & 3) * 8;
  const u16* gB1 = Bt + (col0 + (c1 >> 2)) * 1024 + (c1 & 3) * 8;
  u16* lA0 = lA + (w * 64) * 8;
  u16* lA1 = lA + (256 + w * 64) * 8;
  u16* lB0 = lB + (w * 64) * 8;
  u16* lB1 = lB + (256 + w * 64) * 8;

  f32x4 acc[4][4] = {};

  for (int kt = 0; kt < 1024; kt += 32) {
    gld16(gA0 + kt, lA0);
    gld16(gA1 + kt, lA1);
    gld16(gB0 + kt, lB0);
    gld16(gB1 + kt, lB1);
    __syncthreads();
    bf16x8 aF[4], bF[4];
#pragma unroll
    for (int m = 0; m < 4; ++m)
      aF[m] = *reinterpret_cast<const bf16x8*>(&lA[(wr * 64 + m * 16 + l15) * 32 + l4 * 8]);
#pragma unroll
    for (int n = 0; n < 4; ++n)
      bF[n] = *reinterpret_cast<const bf16x8*>(&lB[(wc * 64 + n * 16 + l15) * 32 + l4 * 8]);
#pragma unroll
    for (int m = 0; m < 4; ++m)
#pragma unroll
      for (int n = 0; n < 4; ++n)
        acc[m][n] = __builtin_amdgcn_mfma_f32_16x16x32_bf16(aF[m], bF[n], acc[m][n], 0, 0, 0);
    __syncthreads();
  }

  float bv[4];
#pragma unroll
  for (int n = 0; n < 4; ++n)
    bv[n] = (EPI == 4) ? 0.0f : bias[col0 + wc * 64 + n * 16 + l15];
#pragma unroll
  for (int m = 0; m < 4; ++m) {
#pragma unroll
    for (int n = 0; n < 4; ++n) {
      const int c = col0 + wc * 64 + n * 16 + l15;
#pragma unroll
      for (int j = 0; j < 4; ++j) {
        const int r = row0 + wr * 64 + m * 16 + l4 * 4 + j;
        const float v = acc[m][n][j] + bv[n];
        if constexpr (EPI == 0 || EPI == 4) {
          outb[r * 1024 + c] = f2bf(v);
        } else if constexpr (EPI == 1) {
          outf[r * 1024 + c] = v;
          outb[r * 1024 + c] = f2bf(v);
        } else if constexpr (EPI == 2) {
          const int bi = r >> 10, s = r & 1023;
          const int h = c >> 6, d = c & 63;
          outb[((bi * 16 + h) * 64 + d) * 1024 + s] = f2bf(v);
        } else {
          outf[r * 1024 + c] = v;
        }
      }
    }
  }
}

template<int EPI, int NB = 64>
__global__ __launch_bounds__(256, 2)
void gemm_k(const u16* __restrict__ A, const u16* __restrict__ Bt,
            const float* __restrict__ bias,
            u16* __restrict__ outb, float* __restrict__ outf)
{
  __shared__ u16 lA[128 * 32];
  __shared__ u16 lB[128 * 32];
  gemm_body<EPI, NB>((int)blockIdx.x, lA, lB, A, Bt, bias, outb, outf);
}

// merged Q/K/V (+ optional 4th job: Wcot = (Wc@Wo)^T, 64 blocks, EPI 4).
// jobs 0,1 -> EPI 0; job 2 -> EPI 2 (Vt). grid = 1536 (pass 2) or 1600 (pass 1).
__global__ __launch_bounds__(256, 2)
void gemm3_k(const u16* __restrict__ A0, const u16* __restrict__ B0,
             const float* __restrict__ c0, u16* __restrict__ o0,
             const u16* __restrict__ A1, const u16* __restrict__ B1,
             const float* __restrict__ c1, u16* __restrict__ o1,
             const u16* __restrict__ A2, const u16* __restrict__ B2,
             const float* __restrict__ c2, u16* __restrict__ o2,
             const u16* __restrict__ A3, const u16* __restrict__ B3,
             u16* __restrict__ o3)
{
  __shared__ u16 lA[128 * 32];
  __shared__ u16 lB[128 * 32];
  const int id = (int)blockIdx.x;
  if (id < 512)       gemm_body<0, 64>(id,        lA, lB, A0, B0, c0, o0, nullptr);
  else if (id < 1024) gemm_body<0, 64>(id - 512,  lA, lB, A1, B1, c1, o1, nullptr);
  else if (id < 1536) gemm_body<2, 64>(id - 1024, lA, lB, A2, B2, c2, o2, nullptr);
  else                gemm_body<4, 8>(id - 1536,  lA, lB, A3, B3, nullptr, o3, nullptr);
}

// ---------------- flash attention v5: swapped-QK^T, in-register softmax -------
// 32x32x16 MFMAs. S^T = mfma(K,Q): lane holds 16 scores of tile for q=lane&31,
// kv = (r&3)+8*(r>>2)+4*(lane>>5). Softmax lane-local; P packed to bf16 via
// v_cvt_pk_bf16_f32 + shfl_xor(32) half-exchange -> PV A-operand from regs.
// Wave-uniform running max + T13 defer-rescale (THR=8). K/V LDS staging,
// T14 async-stage, XCD co-location. (256,4): 4 blocks/CU (grid=1024=4/CU).
__global__ __launch_bounds__(256, 4)
void attn_k(const u16* __restrict__ Q, const u16* __restrict__ K,
            const u16* __restrict__ Vt, const u16* __restrict__ ctx_unused,
            u16* __restrict__ ctx)
{
  __shared__ u16 lK[64 * 72];
  __shared__ u16 lV[64 * 72];
  __shared__ float lsumI[4][32];
  const int id = (int)blockIdx.x;
  const int xcd = id & 7, o = id >> 3;
  const int pair = xcd * 16 + (o >> 3);   // 16 (b,h) pairs per XCD
  const int qt = o & 7;
  const int b = pair >> 4, h = pair & 15;
  const int t = threadIdx.x, w = t >> 6, lane = t & 63;
  const int l31 = lane & 31, hi = lane >> 5;
  const int q0 = qt * 128 + w * 32;
  const u16* Qp = Q + (size_t)b * (1024 * 1024) + h * 64;
  const u16* Kp = K + (size_t)b * (1024 * 1024) + h * 64;
  const u16* Vp = Vt + (size_t)(b * 16 + h) * (64 * 1024);

  // staging slots: thread t owns rows r0 and r0+32, 16B chunk c0 (u16 units)
  const int r0 = t >> 3, c0 = (t & 7) * 8;

  // Q fragments (B-operand: lane holds Q[q=l31][d = ks*16 + hi*8 + i])
  bf16x8 bQ[4];
#pragma unroll
  for (int ks = 0; ks < 4; ++ks)
    bQ[ks] = *reinterpret_cast<const bf16x8*>(&Qp[(q0 + l31) * 1024 + ks * 16 + hi * 8]);

  f32x16 acc[2] = {};
  float lsum = 0.f;
  float m_run = -3.0e38f;

  // prologue: issue tile-0 loads
  bf16x8 sK0, sK1, sV0, sV1;
  sK0 = *reinterpret_cast<const bf16x8*>(&Kp[(r0) * 1024 + c0]);
  sK1 = *reinterpret_cast<const bf16x8*>(&Kp[(r0 + 32) * 1024 + c0]);
  sV0 = *reinterpret_cast<const bf16x8*>(&Vp[r0 * 1024 + c0]);
  sV1 = *reinterpret_cast<const bf16x8*>(&Vp[(r0 + 32) * 1024 + c0]);

  for (int it = 0; it < 16; ++it) {
    const int kv0 = it * 64;
    __syncthreads();   // all waves done reading previous tile
    *reinterpret_cast<bf16x8*>(&lK[r0 * 72 + c0]) = sK0;
    *reinterpret_cast<bf16x8*>(&lK[(r0 + 32) * 72 + c0]) = sK1;
    *reinterpret_cast<bf16x8*>(&lV[r0 * 72 + c0]) = sV0;
    *reinterpret_cast<bf16x8*>(&lV[(r0 + 32) * 72 + c0]) = sV1;
    __syncthreads();   // tile ready
    if (it + 1 < 16) {  // issue next tile: in flight during the whole compute
      const int nk = kv0 + 64;
      sK0 = *reinterpret_cast<const bf16x8*>(&Kp[(nk + r0) * 1024 + c0]);
      sK1 = *reinterpret_cast<const bf16x8*>(&Kp[(nk + r0 + 32) * 1024 + c0]);
      sV0 = *reinterpret_cast<const bf16x8*>(&Vp[r0 * 1024 + nk + c0]);
      sV1 = *reinterpret_cast<const bf16x8*>(&Vp[(r0 + 32) * 1024 + nk + c0]);
    }

    // S^T = K Q^T: rows=kv (regs), cols=q (lanes). 2 kv-tiles of 32.
    f32x16 sS[2] = {};
    __builtin_amdgcn_s_setprio(1);
#pragma unroll
    for (int tt = 0; tt < 2; ++tt) {
#pragma unroll
      for (int ks = 0; ks < 4; ++ks) {
        const bf16x8 aK = *reinterpret_cast<const bf16x8*>(
            &lK[(tt * 32 + l31) * 72 + ks * 16 + hi * 8]);
        sS[tt] = __builtin_amdgcn_mfma_f32_32x32x16_bf16(aK, bQ[ks], sS[tt], 0, 0, 0);
      }
    }
    __builtin_amdgcn_s_setprio(0);

    // wave-uniform tile max
    float tm = sS[0][0];
#pragma unroll
    for (int r = 1; r < 16; ++r) tm = fmaxf(tm, sS[0][r]);
#pragma unroll
    for (int r = 0; r < 16; ++r) tm = fmaxf(tm, sS[1][r]);
#pragma unroll
    for (int d = 1; d < 64; d <<= 1) tm = fmaxf(tm, __shfl_xor(tm, d));
    const float nm = fmaxf(m_run, tm);
    if (nm - m_run > 8.0f) {   // T13 defer-rescale (uniform branch)
      const float psc = __builtin_amdgcn_exp2f(m_run - nm);
#pragma unroll
      for (int dt = 0; dt < 2; ++dt)
#pragma unroll
        for (int r = 0; r < 16; ++r) acc[dt][r] *= psc;
      lsum *= psc;
      m_run = nm;
    }

    // P = exp2(S - m_run); pack to bf16 pairs; half-exchange -> PV A-frags
    unsigned pa[2][2][4];
#pragma unroll
    for (int tt = 0; tt < 2; ++tt) {
      float p[16];
#pragma unroll
      for (int r = 0; r < 16; ++r) {
        p[r] = __builtin_amdgcn_exp2f(sS[tt][r] - m_run);
        lsum += p[r];
      }
      unsigned wv[8];
#pragma unroll
      for (int i = 0; i < 8; ++i) wv[i] = cvtpk(p[2 * i], p[2 * i + 1]);
#pragma unroll
      for (int c = 0; c < 2; ++c) {
        const unsigned pw0 = (unsigned)__shfl_xor((int)wv[4 * c + 0], 32);
        const unsigned pw1 = (unsigned)__shfl_xor((int)wv[4 * c + 1], 32);
        const unsigned pw2 = (unsigned)__shfl_xor((int)wv[4 * c + 2], 32);
        const unsigned pw3 = (unsigned)__shfl_xor((int)wv[4 * c + 3], 32);
        pa[tt][c][0] = hi ? pw2 : wv[4 * c + 0];
        pa[tt][c][1] = hi ? pw3 : wv[4 * c + 1];
        pa[tt][c][2] = hi ? wv[4 * c + 2] : pw0;
        pa[tt][c][3] = hi ? wv[4 * c + 3] : pw1;
      }
    }

    // ctx += P @ V : A = P (rows=q), B = V^T rows (=d) from lV
    __builtin_amdgcn_s_setprio(1);
#pragma unroll
    for (int tt = 0; tt < 2; ++tt)
#pragma unroll
      for (int c = 0; c < 2; ++c) {
        u32x4v pw;
        pw.x = pa[tt][c][0]; pw.y = pa[tt][c][1];
        pw.z = pa[tt][c][2]; pw.w = pa[tt][c][3];
        const bf16x8 aP = __builtin_bit_cast(bf16x8, pw);
#pragma unroll
        for (int dt = 0; dt < 2; ++dt) {
          const bf16x8 bV = *reinterpret_cast<const bf16x8*>(
              &lV[(dt * 32 + l31) * 72 + tt * 32 + c * 16 + hi * 8]);
          acc[dt] = __builtin_amdgcn_mfma_f32_32x32x16_bf16(aP, bV, acc[dt], 0, 0, 0);
        }
      }
    __builtin_amdgcn_s_setprio(0);
  }

  // combine half-wave partial sums; broadcast inverse via per-wave LDS
  const float ltot = lsum + __shfl_xor(lsum, 32);
  if (hi == 0) lsumI[w][l31] = 1.0f / ltot;
  u16* Cp = ctx + (size_t)b * (1024 * 1024) + h * 64;
#pragma unroll
  for (int dt = 0; dt < 2; ++dt)
#pragma unroll
    for (int r = 0; r < 16; ++r) {
      const int q = (r & 3) + 8 * (r >> 2) + 4 * hi;
      const float inv = lsumI[w][q];
      Cp[(q0 + q) * 1024 + dt * 32 + l31] = f2bf(acc[dt][r] * inv);
    }
}

// ---------------- driver ------------------------------------------------------
extern "C" void kernel_launch(void* const* d_in, const int* in_sizes, int n_in,
                              void* d_out, int out_size, void* d_ws, size_t ws_size,
                              hipStream_t stream)
{
  (void)in_sizes; (void)n_in; (void)out_size; (void)ws_size;
  const float* X  = (const float*)d_in[0];
  const float* Y  = (const float*)d_in[1];
  const float* Wq = (const float*)d_in[2];
  const float* bq = (const float*)d_in[3];
  const float* Wk = (const float*)d_in[4];
  const float* bk = (const float*)d_in[5];
  const float* Wv = (const float*)d_in[6];
  const float* bv = (const float*)d_in[7];
  const float* Wg = (const float*)d_in[8];
  const float* bg = (const float*)d_in[9];
  const float* Wb = (const float*)d_in[10];
  const float* bb = (const float*)d_in[11];
  const float* Wo = (const float*)d_in[12];
  const float* bo = (const float*)d_in[13];
  float* out = (float*)d_out;
  char* ws = (char*)d_ws;
  const size_t MB = 1024ull * 1024ull;

  u16* Wqt = (u16*)(ws + 0 * MB);
  u16* Wkt = (u16*)(ws + 2 * MB);
  u16* Wvt = (u16*)(ws + 4 * MB);
  u16* Wcn = (u16*)(ws + 6 * MB);    // Wc = 8*Wg+Wb, non-transposed bf16
  u16* Wot = (u16*)(ws + 8 * MB);
  u16* Wcot = (u16*)(ws + 10 * MB);  // (Wc @ Wo)^T bf16
  u16* Xb = (u16*)(ws + 12 * MB);
  u16* Yb = (u16*)(ws + 28 * MB);   // original Y bf16; later reused for Y_new bf16
  u16* Qb = (u16*)(ws + 44 * MB);
  u16* Kb = (u16*)(ws + 60 * MB);
  u16* Vt = (u16*)(ws + 76 * MB);
  u16* Cx = (u16*)(ws + 92 * MB);
  float* bqs = (float*)(ws + 108 * MB);
  float* bcs = (float*)(ws + 108 * MB + 4096);
  float* bco = (float*)(ws + 108 * MB + 8192);
  const int NEL = 8 * 1024 * 1024;

  prep_w<<<dim3(32, 32, 5), dim3(32, 8), 0, stream>>>(Wq, Wk, Wv, Wg, Wb, Wo,
                                                      Wqt, Wkt, Wvt, Wcn, Wot);
  prep_b<<<4, 256, 0, stream>>>(bq, bg, bb, bqs, bcs);
  bias_dot<<<1024, 256, 0, stream>>>(bcs, Wot, bo, bco);
  cvt2_bf16<<<2048, 256, 0, stream>>>(X, Xb, Y, Yb, NEL);

  // pass 1: queries from X, kv from Y -> Y_new. Job 3: Wcot=(Wc@Wo)^T (64 blks)
  gemm3_k<<<1600, 256, 0, stream>>>(Xb, Wqt, bqs, Qb,
                                    Yb, Wkt, bk, Kb,
                                    Yb, Wvt, bv, Vt,
                                    Wot, Wcn, Wcot);
  attn_k<<<dim3(1024), 256, 0, stream>>>(Qb, Kb, Vt, nullptr, Cx);
  gemm_k<1><<<512, 256, 0, stream>>>(Cx, Wcot, bco, Yb, out + NEL);   // Y_new (f32+bf16)

  // pass 2: queries from Y_new, kv from X -> X_new
  gemm3_k<<<1536, 256, 0, stream>>>(Yb, Wqt, bqs, Qb,
                                    Xb, Wkt, bk, Kb,
                                    Xb, Wvt, bv, Vt,
                                    nullptr, nullptr, nullptr);
  attn_k<<<dim3(1024), 256, 0, stream>>>(Qb, Kb, Vt, nullptr, Cx);
  gemm_k<3><<<512, 256, 0, stream>>>(Cx, Wcot, bco, nullptr, out);    // X_new (f32)
}

// Round 10
// 322.912 us; speedup vs baseline: 1.9754x; 1.0411x over previous
//
#include <hip/hip_runtime.h>

typedef unsigned short u16;
typedef __bf16 bf16x8 __attribute__((ext_vector_type(8)));
typedef float f32x4 __attribute__((ext_vector_type(4)));
typedef float f32x16 __attribute__((ext_vector_type(16)));
typedef u16 u16x4 __attribute__((ext_vector_type(4)));
typedef unsigned int u32x4v __attribute__((ext_vector_type(4)));

#define LOG2E_OVER_8 0.18033688011112043f

__device__ __forceinline__ u16 f2bf(float f) {
  union { float f; unsigned int u; } x{f};
  unsigned int r = (x.u + 0x7fffu + ((x.u >> 16) & 1u)) >> 16;
  return (u16)r;
}

__device__ __forceinline__ float bf2f(u16 v) {
  union { unsigned int u; float f; } x;
  x.u = ((unsigned int)v) << 16;
  return x.f;
}

__device__ __forceinline__ unsigned cvtpk(float a, float b) {
  unsigned r;
  asm("v_cvt_pk_bf16_f32 %0, %1, %2" : "=v"(r) : "v"(a), "v"(b));
  return r;
}

__device__ __forceinline__ void gld16(const void* g, void* l) {
  __builtin_amdgcn_global_load_lds((const __attribute__((address_space(1))) unsigned int*)g,
                                   (__attribute__((address_space(3))) unsigned int*)l,
                                   16, 0, 0);
}

// ---------------- weight prep -------------------------------------------------
// m=0: Wqt = (Wq*log2e/8)^T   m=1: Wkt = Wk^T   m=2: Wvt = Wv^T
// m=3: Wcn = 8*Wg + Wbeta, NON-transposed bf16   m=4: Wot = Wo^T
__global__ void prep_w(const float* __restrict__ Wq, const float* __restrict__ Wk,
                       const float* __restrict__ Wv, const float* __restrict__ Wg,
                       const float* __restrict__ Wb, const float* __restrict__ Wo,
                       u16* __restrict__ Wqt, u16* __restrict__ Wkt, u16* __restrict__ Wvt,
                       u16* __restrict__ Wcn, u16* __restrict__ Wot)
{
  __shared__ float tile[32][33];
  const int m = blockIdx.z;
  const int nb = blockIdx.x * 32, kb = blockIdx.y * 32;
  const int tx = threadIdx.x, ty = threadIdx.y;
  const float* src = (m == 0) ? Wq : (m == 1) ? Wk : (m == 2) ? Wv : (m == 3) ? Wg : Wo;
  u16* dst = (m == 0) ? Wqt : (m == 1) ? Wkt : (m == 2) ? Wvt : (m == 3) ? Wcn : Wot;
#pragma unroll
  for (int i = 0; i < 4; ++i) {
    const int k = kb + ty + i * 8;
    float v = src[k * 1024 + nb + tx];
    if (m == 3) v = 8.0f * v + Wb[k * 1024 + nb + tx];
    if (m == 0) v *= LOG2E_OVER_8;
    if (m == 3) dst[k * 1024 + nb + tx] = f2bf(v);   // direct, non-transposed
    else        tile[ty + i * 8][tx] = v;
  }
  __syncthreads();
  if (m != 3) {
#pragma unroll
    for (int i = 0; i < 4; ++i) {
      const int r = ty + i * 8;
      dst[(nb + r) * 1024 + kb + tx] = f2bf(tile[tx][r]);
    }
  }
}

__global__ void prep_b(const float* __restrict__ bq, const float* __restrict__ bg,
                       const float* __restrict__ bb,
                       float* __restrict__ bqs, float* __restrict__ bcs)
{
  const int i = blockIdx.x * 256 + threadIdx.x;
  if (i < 1024) {
    bqs[i] = bq[i] * LOG2E_OVER_8;
    bcs[i] = 8.0f * bg[i] + bb[i];
  }
}

// bco[n] = dot(bcs, Wot-row-n) + bo[n]; 1024 blocks x 256 threads, coalesced
__global__ void bias_dot(const float* __restrict__ bcs, const u16* __restrict__ Wot,
                         const float* __restrict__ bo, float* __restrict__ bco)
{
  __shared__ float part[4];
  const int n = blockIdx.x, t = threadIdx.x;
  const u16* row = Wot + n * 1024;
  float a = 0.f;
#pragma unroll
  for (int i = 0; i < 4; ++i) {
    const int m = t + i * 256;
    a += bcs[m] * bf2f(row[m]);
  }
#pragma unroll
  for (int d = 1; d < 64; d <<= 1) a += __shfl_xor(a, d);
  if ((t & 63) == 0) part[t >> 6] = a;
  __syncthreads();
  if (t == 0) bco[n] = part[0] + part[1] + part[2] + part[3] + bo[n];
}

// ---------------- f32 -> bf16 convert (both tensors, one dispatch) -----------
__global__ void cvt2_bf16(const float* __restrict__ in0, u16* __restrict__ out0,
                          const float* __restrict__ in1, u16* __restrict__ out1, int n)
{
  int i = (blockIdx.x * blockDim.x + threadIdx.x) * 4;
  const int stride = gridDim.x * blockDim.x * 4;
  for (; i < n; i += stride) {
    const float4 v0 = *reinterpret_cast<const float4*>(in0 + i);
    u16x4 o0;
    o0.x = f2bf(v0.x); o0.y = f2bf(v0.y); o0.z = f2bf(v0.z); o0.w = f2bf(v0.w);
    *reinterpret_cast<u16x4*>(out0 + i) = o0;
    const float4 v1 = *reinterpret_cast<const float4*>(in1 + i);
    u16x4 o1;
    o1.x = f2bf(v1.x); o1.y = f2bf(v1.y); o1.z = f2bf(v1.z); o1.w = f2bf(v1.w);
    *reinterpret_cast<u16x4*>(out1 + i) = o1;
  }
}

// ---------------- GEMM body: C[NB*128 x 1024] = A @ Bt^T + bias ---------------
// EPI: 0 = bf16 out; 1 = fp32 + bf16 out; 2 = bf16 out transposed per head
//      Vt[b][h][d][s]; 3 = fp32 out only; 4 = bf16 out, NO bias.
template<int EPI, int NB>
__device__ __forceinline__ void gemm_body(int bid0, u16* lA, u16* lB,
                                          const u16* __restrict__ A,
                                          const u16* __restrict__ Bt,
                                          const float* __restrict__ bias,
                                          u16* __restrict__ outb, float* __restrict__ outf)
{
  int bid = (bid0 & 7) * NB + (bid0 >> 3);   // XCD-contiguous row bands (grid%8==0)
  const int row0 = (bid >> 3) * 128;
  const int col0 = (bid & 7) * 128;
  const int t = threadIdx.x;
  const int w = t >> 6, lane = t & 63;
  const int l15 = lane & 15, l4 = lane >> 4;
  const int wr = w >> 1, wc = w & 1;

  const int c0 = t, c1 = 256 + t;
  const u16* gA0 = A + (row0 + (c0 >> 2)) * 1024 + (c0 & 3) * 8;
  const u16* gA1 = A + (row0 + (c1 >> 2)) * 1024 + (c1 & 3) * 8;
  const u16* gB0 = Bt + (col0 + (c0 >> 2)) * 1024 + (c0 & 3) * 8;
  const u16* gB1 = Bt + (col0 + (c1 >> 2)) * 1024 + (c1 & 3) * 8;
  u16* lA0 = lA + (w * 64) * 8;
  u16* lA1 = lA + (256 + w * 64) * 8;
  u16* lB0 = lB + (w * 64) * 8;
  u16* lB1 = lB + (256 + w * 64) * 8;

  f32x4 acc[4][4] = {};

  for (int kt = 0; kt < 1024; kt += 32) {
    gld16(gA0 + kt, lA0);
    gld16(gA1 + kt, lA1);
    gld16(gB0 + kt, lB0);
    gld16(gB1 + kt, lB1);
    __syncthreads();
    bf16x8 aF[4], bF[4];
#pragma unroll
    for (int m = 0; m < 4; ++m)
      aF[m] = *reinterpret_cast<const bf16x8*>(&lA[(wr * 64 + m * 16 + l15) * 32 + l4 * 8]);
#pragma unroll
    for (int n = 0; n < 4; ++n)
      bF[n] = *reinterpret_cast<const bf16x8*>(&lB[(wc * 64 + n * 16 + l15) * 32 + l4 * 8]);
#pragma unroll
    for (int m = 0; m < 4; ++m)
#pragma unroll
      for (int n = 0; n < 4; ++n)
        acc[m][n] = __builtin_amdgcn_mfma_f32_16x16x32_bf16(aF[m], bF[n], acc[m][n], 0, 0, 0);
    __syncthreads();
  }

  float bv[4];
#pragma unroll
  for (int n = 0; n < 4; ++n)
    bv[n] = (EPI == 4) ? 0.0f : bias[col0 + wc * 64 + n * 16 + l15];
#pragma unroll
  for (int m = 0; m < 4; ++m) {
#pragma unroll
    for (int n = 0; n < 4; ++n) {
      const int c = col0 + wc * 64 + n * 16 + l15;
#pragma unroll
      for (int j = 0; j < 4; ++j) {
        const int r = row0 + wr * 64 + m * 16 + l4 * 4 + j;
        const float v = acc[m][n][j] + bv[n];
        if constexpr (EPI == 0 || EPI == 4) {
          outb[r * 1024 + c] = f2bf(v);
        } else if constexpr (EPI == 1) {
          outf[r * 1024 + c] = v;
          outb[r * 1024 + c] = f2bf(v);
        } else if constexpr (EPI == 2) {
          const int bi = r >> 10, s = r & 1023;
          const int h = c >> 6, d = c & 63;
          outb[((bi * 16 + h) * 64 + d) * 1024 + s] = f2bf(v);
        } else {
          outf[r * 1024 + c] = v;
        }
      }
    }
  }
}

template<int EPI, int NB = 64>
__global__ __launch_bounds__(256, 2)
void gemm_k(const u16* __restrict__ A, const u16* __restrict__ Bt,
            const float* __restrict__ bias,
            u16* __restrict__ outb, float* __restrict__ outf)
{
  __shared__ u16 lA[128 * 32];
  __shared__ u16 lB[128 * 32];
  gemm_body<EPI, NB>((int)blockIdx.x, lA, lB, A, Bt, bias, outb, outf);
}

// merged Q/K/V (+ optional 4th job: Wcot = (Wc@Wo)^T, 64 blocks, EPI 4).
// jobs 0,1 -> EPI 0; job 2 -> EPI 2 (Vt). grid = 1536 (pass 2) or 1600 (pass 1).
__global__ __launch_bounds__(256, 2)
void gemm3_k(const u16* __restrict__ A0, const u16* __restrict__ B0,
             const float* __restrict__ c0, u16* __restrict__ o0,
             const u16* __restrict__ A1, const u16* __restrict__ B1,
             const float* __restrict__ c1, u16* __restrict__ o1,
             const u16* __restrict__ A2, const u16* __restrict__ B2,
             const float* __restrict__ c2, u16* __restrict__ o2,
             const u16* __restrict__ A3, const u16* __restrict__ B3,
             u16* __restrict__ o3)
{
  __shared__ u16 lA[128 * 32];
  __shared__ u16 lB[128 * 32];
  const int id = (int)blockIdx.x;
  if (id < 512)       gemm_body<0, 64>(id,        lA, lB, A0, B0, c0, o0, nullptr);
  else if (id < 1024) gemm_body<0, 64>(id - 512,  lA, lB, A1, B1, c1, o1, nullptr);
  else if (id < 1536) gemm_body<2, 64>(id - 1024, lA, lB, A2, B2, c2, o2, nullptr);
  else                gemm_body<4, 8>(id - 1536,  lA, lB, A3, B3, nullptr, o3, nullptr);
}

// ---------------- flash attention v6: no-max softmax --------------------------
// 32x32x16 MFMAs, swapped operands: S^T = mfma(K,Q), lane holds 16 scores for
// q=lane&31, kv=(r&3)+8*(r>>2)+4*(lane>>5). Scores are log2-scaled upstream
// (Wq,bq folded with log2e/8). |S| <= ~97 worst case and f32/bf16 both have
// 8-bit exponents, so exp2(S) can never overflow/underflow and bf16 relative
// precision is magnitude-independent -> NO running max, NO rescale (softmax is
// shift-invariant; divide by sum at the end). P packed via v_cvt_pk_bf16_f32 +
// shfl_xor(32) half-exchange, PV A-operand straight from registers.
// K/V LDS staging + T14 async-stage + XCD co-location as before.
__global__ __launch_bounds__(256, 4)
void attn_k(const u16* __restrict__ Q, const u16* __restrict__ K,
            const u16* __restrict__ Vt, const u16* __restrict__ ctx_unused,
            u16* __restrict__ ctx)
{
  __shared__ u16 lK[64 * 72];
  __shared__ u16 lV[64 * 72];
  __shared__ float lsumI[4][32];
  const int id = (int)blockIdx.x;
  const int xcd = id & 7, o = id >> 3;
  const int pair = xcd * 16 + (o >> 3);   // 16 (b,h) pairs per XCD
  const int qt = o & 7;
  const int b = pair >> 4, h = pair & 15;
  const int t = threadIdx.x, w = t >> 6, lane = t & 63;
  const int l31 = lane & 31, hi = lane >> 5;
  const int q0 = qt * 128 + w * 32;
  const u16* Qp = Q + (size_t)b * (1024 * 1024) + h * 64;
  const u16* Kp = K + (size_t)b * (1024 * 1024) + h * 64;
  const u16* Vp = Vt + (size_t)(b * 16 + h) * (64 * 1024);

  // staging slots: thread t owns rows r0 and r0+32, 16B chunk c0 (u16 units)
  const int r0 = t >> 3, c0 = (t & 7) * 8;

  // Q fragments (B-operand: lane holds Q[q=l31][d = ks*16 + hi*8 + i])
  bf16x8 bQ[4];
#pragma unroll
  for (int ks = 0; ks < 4; ++ks)
    bQ[ks] = *reinterpret_cast<const bf16x8*>(&Qp[(q0 + l31) * 1024 + ks * 16 + hi * 8]);

  f32x16 acc[2] = {};
  float lsum = 0.f;

  // prologue: issue tile-0 loads
  bf16x8 sK0, sK1, sV0, sV1;
  sK0 = *reinterpret_cast<const bf16x8*>(&Kp[(r0) * 1024 + c0]);
  sK1 = *reinterpret_cast<const bf16x8*>(&Kp[(r0 + 32) * 1024 + c0]);
  sV0 = *reinterpret_cast<const bf16x8*>(&Vp[r0 * 1024 + c0]);
  sV1 = *reinterpret_cast<const bf16x8*>(&Vp[(r0 + 32) * 1024 + c0]);

  for (int it = 0; it < 16; ++it) {
    const int kv0 = it * 64;
    __syncthreads();   // all waves done reading previous tile
    *reinterpret_cast<bf16x8*>(&lK[r0 * 72 + c0]) = sK0;
    *reinterpret_cast<bf16x8*>(&lK[(r0 + 32) * 72 + c0]) = sK1;
    *reinterpret_cast<bf16x8*>(&lV[r0 * 72 + c0]) = sV0;
    *reinterpret_cast<bf16x8*>(&lV[(r0 + 32) * 72 + c0]) = sV1;
    __syncthreads();   // tile ready
    if (it + 1 < 16) {  // issue next tile: in flight during the whole compute
      const int nk = kv0 + 64;
      sK0 = *reinterpret_cast<const bf16x8*>(&Kp[(nk + r0) * 1024 + c0]);
      sK1 = *reinterpret_cast<const bf16x8*>(&Kp[(nk + r0 + 32) * 1024 + c0]);
      sV0 = *reinterpret_cast<const bf16x8*>(&Vp[r0 * 1024 + nk + c0]);
      sV1 = *reinterpret_cast<const bf16x8*>(&Vp[(r0 + 32) * 1024 + nk + c0]);
    }

    // S^T = K Q^T: rows=kv (regs), cols=q (lanes). 2 kv-tiles of 32.
    f32x16 sS[2] = {};
    __builtin_amdgcn_s_setprio(1);
#pragma unroll
    for (int tt = 0; tt < 2; ++tt) {
#pragma unroll
      for (int ks = 0; ks < 4; ++ks) {
        const bf16x8 aK = *reinterpret_cast<const bf16x8*>(
            &lK[(tt * 32 + l31) * 72 + ks * 16 + hi * 8]);
        sS[tt] = __builtin_amdgcn_mfma_f32_32x32x16_bf16(aK, bQ[ks], sS[tt], 0, 0, 0);
      }
    }
    __builtin_amdgcn_s_setprio(0);

    // P = exp2(S) directly (no shift needed: |S| bounded, e8 exponent range);
    // pack to bf16 pairs; half-exchange -> PV A-frags
    unsigned pa[2][2][4];
#pragma unroll
    for (int tt = 0; tt < 2; ++tt) {
      float p[16];
      float s0 = 0.f, s1 = 0.f, s2 = 0.f, s3 = 0.f;
#pragma unroll
      for (int r = 0; r < 16; r += 4) {
        p[r]     = __builtin_amdgcn_exp2f(sS[tt][r]);
        p[r + 1] = __builtin_amdgcn_exp2f(sS[tt][r + 1]);
        p[r + 2] = __builtin_amdgcn_exp2f(sS[tt][r + 2]);
        p[r + 3] = __builtin_amdgcn_exp2f(sS[tt][r + 3]);
        s0 += p[r]; s1 += p[r + 1]; s2 += p[r + 2]; s3 += p[r + 3];
      }
      lsum += (s0 + s1) + (s2 + s3);
      unsigned wv[8];
#pragma unroll
      for (int i = 0; i < 8; ++i) wv[i] = cvtpk(p[2 * i], p[2 * i + 1]);
#pragma unroll
      for (int c = 0; c < 2; ++c) {
        const unsigned pw0 = (unsigned)__shfl_xor((int)wv[4 * c + 0], 32);
        const unsigned pw1 = (unsigned)__shfl_xor((int)wv[4 * c + 1], 32);
        const unsigned pw2 = (unsigned)__shfl_xor((int)wv[4 * c + 2], 32);
        const unsigned pw3 = (unsigned)__shfl_xor((int)wv[4 * c + 3], 32);
        pa[tt][c][0] = hi ? pw2 : wv[4 * c + 0];
        pa[tt][c][1] = hi ? pw3 : wv[4 * c + 1];
        pa[tt][c][2] = hi ? wv[4 * c + 2] : pw0;
        pa[tt][c][3] = hi ? wv[4 * c + 3] : pw1;
      }
    }

    // ctx += P @ V : A = P (rows=q), B = V^T rows (=d) from lV
    __builtin_amdgcn_s_setprio(1);
#pragma unroll
    for (int tt = 0; tt < 2; ++tt)
#pragma unroll
      for (int c = 0; c < 2; ++c) {
        u32x4v pw;
        pw.x = pa[tt][c][0]; pw.y = pa[tt][c][1];
        pw.z = pa[tt][c][2]; pw.w = pa[tt][c][3];
        const bf16x8 aP = __builtin_bit_cast(bf16x8, pw);
#pragma unroll
        for (int dt = 0; dt < 2; ++dt) {
          const bf16x8 bV = *reinterpret_cast<const bf16x8*>(
              &lV[(dt * 32 + l31) * 72 + tt * 32 + c * 16 + hi * 8]);
          acc[dt] = __builtin_amdgcn_mfma_f32_32x32x16_bf16(aP, bV, acc[dt], 0, 0, 0);
        }
      }
    __builtin_amdgcn_s_setprio(0);
  }

  // combine half-wave partial sums; broadcast inverse via per-wave LDS
  const float ltot = lsum + __shfl_xor(lsum, 32);
  if (hi == 0) lsumI[w][l31] = 1.0f / ltot;
  u16* Cp = ctx + (size_t)b * (1024 * 1024) + h * 64;
#pragma unroll
  for (int dt = 0; dt < 2; ++dt)
#pragma unroll
    for (int r = 0; r < 16; ++r) {
      const int q = (r & 3) + 8 * (r >> 2) + 4 * hi;
      const float inv = lsumI[w][q];
      Cp[(q0 + q) * 1024 + dt * 32 + l31] = f2bf(acc[dt][r] * inv);
    }
}

// ---------------- driver ------------------------------------------------------
extern "C" void kernel_launch(void* const* d_in, const int* in_sizes, int n_in,
                              void* d_out, int out_size, void* d_ws, size_t ws_size,
                              hipStream_t stream)
{
  (void)in_sizes; (void)n_in; (void)out_size; (void)ws_size;
  const float* X  = (const float*)d_in[0];
  const float* Y  = (const float*)d_in[1];
  const float* Wq = (const float*)d_in[2];
  const float* bq = (const float*)d_in[3];
  const float* Wk = (const float*)d_in[4];
  const float* bk = (const float*)d_in[5];
  const float* Wv = (const float*)d_in[6];
  const float* bv = (const float*)d_in[7];
  const float* Wg = (const float*)d_in[8];
  const float* bg = (const float*)d_in[9];
  const float* Wb = (const float*)d_in[10];
  const float* bb = (const float*)d_in[11];
  const float* Wo = (const float*)d_in[12];
  const float* bo = (const float*)d_in[13];
  float* out = (float*)d_out;
  char* ws = (char*)d_ws;
  const size_t MB = 1024ull * 1024ull;

  u16* Wqt = (u16*)(ws + 0 * MB);
  u16* Wkt = (u16*)(ws + 2 * MB);
  u16* Wvt = (u16*)(ws + 4 * MB);
  u16* Wcn = (u16*)(ws + 6 * MB);    // Wc = 8*Wg+Wb, non-transposed bf16
  u16* Wot = (u16*)(ws + 8 * MB);
  u16* Wcot = (u16*)(ws + 10 * MB);  // (Wc @ Wo)^T bf16
  u16* Xb = (u16*)(ws + 12 * MB);
  u16* Yb = (u16*)(ws + 28 * MB);   // original Y bf16; later reused for Y_new bf16
  u16* Qb = (u16*)(ws + 44 * MB);
  u16* Kb = (u16*)(ws + 60 * MB);
  u16* Vt = (u16*)(ws + 76 * MB);
  u16* Cx = (u16*)(ws + 92 * MB);
  float* bqs = (float*)(ws + 108 * MB);
  float* bcs = (float*)(ws + 108 * MB + 4096);
  float* bco = (float*)(ws + 108 * MB + 8192);
  const int NEL = 8 * 1024 * 1024;

  prep_w<<<dim3(32, 32, 5), dim3(32, 8), 0, stream>>>(Wq, Wk, Wv, Wg, Wb, Wo,
                                                      Wqt, Wkt, Wvt, Wcn, Wot);
  prep_b<<<4, 256, 0, stream>>>(bq, bg, bb, bqs, bcs);
  bias_dot<<<1024, 256, 0, stream>>>(bcs, Wot, bo, bco);
  cvt2_bf16<<<2048, 256, 0, stream>>>(X, Xb, Y, Yb, NEL);

  // pass 1: queries from X, kv from Y -> Y_new. Job 3: Wcot=(Wc@Wo)^T (64 blks)
  gemm3_k<<<1600, 256, 0, stream>>>(Xb, Wqt, bqs, Qb,
                                    Yb, Wkt, bk, Kb,
                                    Yb, Wvt, bv, Vt,
                                    Wot, Wcn, Wcot);
  attn_k<<<dim3(1024), 256, 0, stream>>>(Qb, Kb, Vt, nullptr, Cx);
  gemm_k<1><<<512, 256, 0, stream>>>(Cx, Wcot, bco, Yb, out + NEL);   // Y_new (f32+bf16)

  // pass 2: queries from Y_new, kv from X -> X_new
  gemm3_k<<<1536, 256, 0, stream>>>(Yb, Wqt, bqs, Qb,
                                    Xb, Wkt, bk, Kb,
                                    Xb, Wvt, bv, Vt,
                                    nullptr, nullptr, nullptr);
  attn_k<<<dim3(1024), 256, 0, stream>>>(Qb, Kb, Vt, nullptr, Cx);
  gemm_k<3><<<512, 256, 0, stream>>>(Cx, Wcot, bco, nullptr, out);    // X_new (f32)
}

// Round 11
// 286.289 us; speedup vs baseline: 2.2281x; 1.1279x over previous
//
#include <hip/hip_runtime.h>

typedef unsigned short u16;
typedef __bf16 bf16x8 __attribute__((ext_vector_type(8)));
typedef float f32x4 __attribute__((ext_vector_type(4)));
typedef float f32x16 __attribute__((ext_vector_type(16)));
typedef u16 u16x4 __attribute__((ext_vector_type(4)));
typedef unsigned int u32x4v __attribute__((ext_vector_type(4)));

#define LOG2E_OVER_8 0.18033688011112043f

__device__ __forceinline__ u16 f2bf(float f) {
  union { float f; unsigned int u; } x{f};
  unsigned int r = (x.u + 0x7fffu + ((x.u >> 16) & 1u)) >> 16;
  return (u16)r;
}

__device__ __forceinline__ float bf2f(u16 v) {
  union { unsigned int u; float f; } x;
  x.u = ((unsigned int)v) << 16;
  return x.f;
}

__device__ __forceinline__ unsigned cvtpk(float a, float b) {
  unsigned r;
  asm("v_cvt_pk_bf16_f32 %0, %1, %2" : "=v"(r) : "v"(a), "v"(b));
  return r;
}

__device__ __forceinline__ void gld16(const void* g, void* l) {
  __builtin_amdgcn_global_load_lds((const __attribute__((address_space(1))) unsigned int*)g,
                                   (__attribute__((address_space(3))) unsigned int*)l,
                                   16, 0, 0);
}

// ---------------- weight prep -------------------------------------------------
// m=0: Wqt = (Wq*log2e/8)^T   m=1: Wkt = Wk^T   m=2: Wvt = Wv^T
// m=3: Wcn = 8*Wg + Wbeta, NON-transposed bf16   m=4: Wot = Wo^T
__global__ void prep_w(const float* __restrict__ Wq, const float* __restrict__ Wk,
                       const float* __restrict__ Wv, const float* __restrict__ Wg,
                       const float* __restrict__ Wb, const float* __restrict__ Wo,
                       u16* __restrict__ Wqt, u16* __restrict__ Wkt, u16* __restrict__ Wvt,
                       u16* __restrict__ Wcn, u16* __restrict__ Wot)
{
  __shared__ float tile[32][33];
  const int m = blockIdx.z;
  const int nb = blockIdx.x * 32, kb = blockIdx.y * 32;
  const int tx = threadIdx.x, ty = threadIdx.y;
  const float* src = (m == 0) ? Wq : (m == 1) ? Wk : (m == 2) ? Wv : (m == 3) ? Wg : Wo;
  u16* dst = (m == 0) ? Wqt : (m == 1) ? Wkt : (m == 2) ? Wvt : (m == 3) ? Wcn : Wot;
#pragma unroll
  for (int i = 0; i < 4; ++i) {
    const int k = kb + ty + i * 8;
    float v = src[k * 1024 + nb + tx];
    if (m == 3) v = 8.0f * v + Wb[k * 1024 + nb + tx];
    if (m == 0) v *= LOG2E_OVER_8;
    if (m == 3) dst[k * 1024 + nb + tx] = f2bf(v);   // direct, non-transposed
    else        tile[ty + i * 8][tx] = v;
  }
  __syncthreads();
  if (m != 3) {
#pragma unroll
    for (int i = 0; i < 4; ++i) {
      const int r = ty + i * 8;
      dst[(nb + r) * 1024 + kb + tx] = f2bf(tile[tx][r]);
    }
  }
}

__global__ void prep_b(const float* __restrict__ bq, const float* __restrict__ bg,
                       const float* __restrict__ bb,
                       float* __restrict__ bqs, float* __restrict__ bcs)
{
  const int i = blockIdx.x * 256 + threadIdx.x;
  if (i < 1024) {
    bqs[i] = bq[i] * LOG2E_OVER_8;
    bcs[i] = 8.0f * bg[i] + bb[i];
  }
}

// ---------------- f32 -> bf16 convert (both tensors, one dispatch) -----------
__global__ void cvt2_bf16(const float* __restrict__ in0, u16* __restrict__ out0,
                          const float* __restrict__ in1, u16* __restrict__ out1, int n)
{
  int i = (blockIdx.x * blockDim.x + threadIdx.x) * 4;
  const int stride = gridDim.x * blockDim.x * 4;
  for (; i < n; i += stride) {
    const float4 v0 = *reinterpret_cast<const float4*>(in0 + i);
    u16x4 o0;
    o0.x = f2bf(v0.x); o0.y = f2bf(v0.y); o0.z = f2bf(v0.z); o0.w = f2bf(v0.w);
    *reinterpret_cast<u16x4*>(out0 + i) = o0;
    const float4 v1 = *reinterpret_cast<const float4*>(in1 + i);
    u16x4 o1;
    o1.x = f2bf(v1.x); o1.y = f2bf(v1.y); o1.z = f2bf(v1.z); o1.w = f2bf(v1.w);
    *reinterpret_cast<u16x4*>(out1 + i) = o1;
  }
}

// ---------------- GEMM body: C[NB*128 x 1024] = A @ Bt^T + bias ---------------
// BK=64 with XOR-swizzled LDS (G21 both-sides pattern): gld16 dest stays
// LINEAR; per-lane global SOURCE col16 is pre-swizzled (col ^ row&7); fragment
// reads apply the same XOR -> 16-lane b128 phases hit 8 distinct 4-bank spans,
// 2 lanes each (free, m136). 16 K-iters (half the barrier drains of BK=32).
// EPI: 0 = bf16 out; 1 = fp32 + bf16 out; 2 = bf16 out transposed per head
//      Vt[b][h][d][s]; 3 = fp32 out only; 4 = bf16 out, NO bias.
template<int EPI, int NB>
__device__ __forceinline__ void gemm_body(int bid0, u16* lA, u16* lB,
                                          const u16* __restrict__ A,
                                          const u16* __restrict__ Bt,
                                          const float* __restrict__ bias,
                                          u16* __restrict__ outb, float* __restrict__ outf)
{
  int bid = (bid0 & 7) * NB + (bid0 >> 3);   // XCD-contiguous row bands (grid%8==0)
  const int row0 = (bid >> 3) * 128;
  const int col0 = (bid & 7) * 128;
  const int t = threadIdx.x;
  const int w = t >> 6, lane = t & 63;
  const int l15 = lane & 15, l4 = lane >> 4;
  const int wr = w >> 1, wc = w & 1;
  const int l7 = l15 & 7;

  // staging: 1024 16B-chunks per 128x64 tile; thread t owns c = k2*256+t.
  // row = c>>3, source col16 pre-swizzled by row&7 (LDS dest stays linear).
  const u16* gA[4];
  const u16* gB[4];
#pragma unroll
  for (int k2 = 0; k2 < 4; ++k2) {
    const int c = k2 * 256 + t;
    const int r = c >> 3;
    const int sc = ((c & 7) ^ (r & 7)) * 8;
    gA[k2] = A + (row0 + r) * 1024 + sc;
    gB[k2] = Bt + (col0 + r) * 1024 + sc;
  }

  f32x4 acc[4][4] = {};

  for (int kt = 0; kt < 1024; kt += 64) {
#pragma unroll
    for (int k2 = 0; k2 < 4; ++k2) {
      gld16(gA[k2] + kt, lA + (k2 * 256 + w * 64) * 8);
      gld16(gB[k2] + kt, lB + (k2 * 256 + w * 64) * 8);
    }
    __syncthreads();
    bf16x8 aF[4][2], bF[4][2];
#pragma unroll
    for (int m = 0; m < 4; ++m)
#pragma unroll
      for (int ks = 0; ks < 2; ++ks)
        aF[m][ks] = *reinterpret_cast<const bf16x8*>(
            &lA[(wr * 64 + m * 16 + l15) * 64 + ((ks * 4 + l4) ^ l7) * 8]);
#pragma unroll
    for (int n = 0; n < 4; ++n)
#pragma unroll
      for (int ks = 0; ks < 2; ++ks)
        bF[n][ks] = *reinterpret_cast<const bf16x8*>(
            &lB[(wc * 64 + n * 16 + l15) * 64 + ((ks * 4 + l4) ^ l7) * 8]);
#pragma unroll
    for (int m = 0; m < 4; ++m)
#pragma unroll
      for (int n = 0; n < 4; ++n) {
        acc[m][n] = __builtin_amdgcn_mfma_f32_16x16x32_bf16(aF[m][0], bF[n][0], acc[m][n], 0, 0, 0);
        acc[m][n] = __builtin_amdgcn_mfma_f32_16x16x32_bf16(aF[m][1], bF[n][1], acc[m][n], 0, 0, 0);
      }
    __syncthreads();
  }

  float bv[4];
#pragma unroll
  for (int n = 0; n < 4; ++n)
    bv[n] = (EPI == 4) ? 0.0f : bias[col0 + wc * 64 + n * 16 + l15];
#pragma unroll
  for (int m = 0; m < 4; ++m) {
#pragma unroll
    for (int n = 0; n < 4; ++n) {
      const int c = col0 + wc * 64 + n * 16 + l15;
#pragma unroll
      for (int j = 0; j < 4; ++j) {
        const int r = row0 + wr * 64 + m * 16 + l4 * 4 + j;
        const float v = acc[m][n][j] + bv[n];
        if constexpr (EPI == 0 || EPI == 4) {
          outb[r * 1024 + c] = f2bf(v);
        } else if constexpr (EPI == 1) {
          outf[r * 1024 + c] = v;
          outb[r * 1024 + c] = f2bf(v);
        } else if constexpr (EPI == 2) {
          const int bi = r >> 10, s = r & 1023;
          const int h = c >> 6, d = c & 63;
          outb[((bi * 16 + h) * 64 + d) * 1024 + s] = f2bf(v);
        } else {
          outf[r * 1024 + c] = v;
        }
      }
    }
  }
}

// bias job: bco[n] = dot(bcs, Wot-row-n) + bo[n]; 256 blocks, wave per row
__device__ __forceinline__ void bias_body(int bb, const float* __restrict__ bcs,
                                          const u16* __restrict__ Wot,
                                          const float* __restrict__ bo,
                                          float* __restrict__ bco)
{
  const int t = threadIdx.x, w = t >> 6, l = t & 63;
  const int n = bb * 4 + w;
  const u16* row = Wot + n * 1024;
  float a = 0.f;
#pragma unroll
  for (int i = 0; i < 16; ++i) a += bcs[l + 64 * i] * bf2f(row[l + 64 * i]);
#pragma unroll
  for (int d = 1; d < 64; d <<= 1) a += __shfl_xor(a, d);
  if (l == 0) bco[n] = a + bo[n];
}

template<int EPI, int NB = 64>
__global__ __launch_bounds__(256, 2)
void gemm_k(const u16* __restrict__ A, const u16* __restrict__ Bt,
            const float* __restrict__ bias,
            u16* __restrict__ outb, float* __restrict__ outf)
{
  __shared__ u16 lA[128 * 64];
  __shared__ u16 lB[128 * 64];
  gemm_body<EPI, NB>((int)blockIdx.x, lA, lB, A, Bt, bias, outb, outf);
}

// merged Q/K/V (+ job 3: Wcot = (Wc@Wo)^T, 64 blocks; + job 4: bias_dot,
// 256 blocks). grid = 1856 (pass 1) or 1536 (pass 2).
__global__ __launch_bounds__(256, 2)
void gemm3_k(const u16* __restrict__ A0, const u16* __restrict__ B0,
             const float* __restrict__ c0, u16* __restrict__ o0,
             const u16* __restrict__ A1, const u16* __restrict__ B1,
             const float* __restrict__ c1, u16* __restrict__ o1,
             const u16* __restrict__ A2, const u16* __restrict__ B2,
             const float* __restrict__ c2, u16* __restrict__ o2,
             const u16* __restrict__ A3, const u16* __restrict__ B3,
             u16* __restrict__ o3,
             const float* __restrict__ bcs, const float* __restrict__ bo,
             float* __restrict__ bco)
{
  __shared__ u16 lA[128 * 64];
  __shared__ u16 lB[128 * 64];
  const int id = (int)blockIdx.x;
  if (id < 512)       gemm_body<0, 64>(id,        lA, lB, A0, B0, c0, o0, nullptr);
  else if (id < 1024) gemm_body<0, 64>(id - 512,  lA, lB, A1, B1, c1, o1, nullptr);
  else if (id < 1536) gemm_body<2, 64>(id - 1024, lA, lB, A2, B2, c2, o2, nullptr);
  else if (id < 1600) gemm_body<4, 8>(id - 1536,  lA, lB, A3, B3, nullptr, o3, nullptr);
  else                bias_body(id - 1600, bcs, A3, bo, bco);   // A3 = Wot
}

// ---------------- flash attention v6: no-max softmax --------------------------
// 32x32x16 MFMAs, swapped operands: S^T = mfma(K,Q), lane holds 16 scores for
// q=lane&31, kv=(r&3)+8*(r>>2)+4*(lane>>5). Scores are log2-scaled upstream
// (Wq,bq folded with log2e/8); |S| bounded << 127 so exp2 never over/underflows
// -> no running max, no rescale; divide by sum at the end. P packed via
// v_cvt_pk_bf16_f32 + shfl_xor(32) half-exchange, PV A-operand from registers.
// K/V LDS staging + T14 async-stage + XCD co-location.
__global__ __launch_bounds__(256, 4)
void attn_k(const u16* __restrict__ Q, const u16* __restrict__ K,
            const u16* __restrict__ Vt, const u16* __restrict__ ctx_unused,
            u16* __restrict__ ctx)
{
  __shared__ u16 lK[64 * 72];
  __shared__ u16 lV[64 * 72];
  __shared__ float lsumI[4][32];
  const int id = (int)blockIdx.x;
  const int xcd = id & 7, o = id >> 3;
  const int pair = xcd * 16 + (o >> 3);   // 16 (b,h) pairs per XCD
  const int qt = o & 7;
  const int b = pair >> 4, h = pair & 15;
  const int t = threadIdx.x, w = t >> 6, lane = t & 63;
  const int l31 = lane & 31, hi = lane >> 5;
  const int q0 = qt * 128 + w * 32;
  const u16* Qp = Q + (size_t)b * (1024 * 1024) + h * 64;
  const u16* Kp = K + (size_t)b * (1024 * 1024) + h * 64;
  const u16* Vp = Vt + (size_t)(b * 16 + h) * (64 * 1024);

  // staging slots: thread t owns rows r0 and r0+32, 16B chunk c0 (u16 units)
  const int r0 = t >> 3, c0 = (t & 7) * 8;

  // Q fragments (B-operand: lane holds Q[q=l31][d = ks*16 + hi*8 + i])
  bf16x8 bQ[4];
#pragma unroll
  for (int ks = 0; ks < 4; ++ks)
    bQ[ks] = *reinterpret_cast<const bf16x8*>(&Qp[(q0 + l31) * 1024 + ks * 16 + hi * 8]);

  f32x16 acc[2] = {};
  float lsum = 0.f;

  // prologue: issue tile-0 loads
  bf16x8 sK0, sK1, sV0, sV1;
  sK0 = *reinterpret_cast<const bf16x8*>(&Kp[(r0) * 1024 + c0]);
  sK1 = *reinterpret_cast<const bf16x8*>(&Kp[(r0 + 32) * 1024 + c0]);
  sV0 = *reinterpret_cast<const bf16x8*>(&Vp[r0 * 1024 + c0]);
  sV1 = *reinterpret_cast<const bf16x8*>(&Vp[(r0 + 32) * 1024 + c0]);

  for (int it = 0; it < 16; ++it) {
    const int kv0 = it * 64;
    __syncthreads();   // all waves done reading previous tile
    *reinterpret_cast<bf16x8*>(&lK[r0 * 72 + c0]) = sK0;
    *reinterpret_cast<bf16x8*>(&lK[(r0 + 32) * 72 + c0]) = sK1;
    *reinterpret_cast<bf16x8*>(&lV[r0 * 72 + c0]) = sV0;
    *reinterpret_cast<bf16x8*>(&lV[(r0 + 32) * 72 + c0]) = sV1;
    __syncthreads();   // tile ready
    if (it + 1 < 16) {  // issue next tile: in flight during the whole compute
      const int nk = kv0 + 64;
      sK0 = *reinterpret_cast<const bf16x8*>(&Kp[(nk + r0) * 1024 + c0]);
      sK1 = *reinterpret_cast<const bf16x8*>(&Kp[(nk + r0 + 32) * 1024 + c0]);
      sV0 = *reinterpret_cast<const bf16x8*>(&Vp[r0 * 1024 + nk + c0]);
      sV1 = *reinterpret_cast<const bf16x8*>(&Vp[(r0 + 32) * 1024 + nk + c0]);
    }

    // S^T = K Q^T: rows=kv (regs), cols=q (lanes). 2 kv-tiles of 32.
    f32x16 sS[2] = {};
    __builtin_amdgcn_s_setprio(1);
#pragma unroll
    for (int tt = 0; tt < 2; ++tt) {
#pragma unroll
      for (int ks = 0; ks < 4; ++ks) {
        const bf16x8 aK = *reinterpret_cast<const bf16x8*>(
            &lK[(tt * 32 + l31) * 72 + ks * 16 + hi * 8]);
        sS[tt] = __builtin_amdgcn_mfma_f32_32x32x16_bf16(aK, bQ[ks], sS[tt], 0, 0, 0);
      }
    }
    __builtin_amdgcn_s_setprio(0);

    // P = exp2(S) directly; pack to bf16 pairs; half-exchange -> PV A-frags
    unsigned pa[2][2][4];
#pragma unroll
    for (int tt = 0; tt < 2; ++tt) {
      float p[16];
      float s0 = 0.f, s1 = 0.f, s2 = 0.f, s3 = 0.f;
#pragma unroll
      for (int r = 0; r < 16; r += 4) {
        p[r]     = __builtin_amdgcn_exp2f(sS[tt][r]);
        p[r + 1] = __builtin_amdgcn_exp2f(sS[tt][r + 1]);
        p[r + 2] = __builtin_amdgcn_exp2f(sS[tt][r + 2]);
        p[r + 3] = __builtin_amdgcn_exp2f(sS[tt][r + 3]);
        s0 += p[r]; s1 += p[r + 1]; s2 += p[r + 2]; s3 += p[r + 3];
      }
      lsum += (s0 + s1) + (s2 + s3);
      unsigned wv[8];
#pragma unroll
      for (int i = 0; i < 8; ++i) wv[i] = cvtpk(p[2 * i], p[2 * i + 1]);
#pragma unroll
      for (int c = 0; c < 2; ++c) {
        const unsigned pw0 = (unsigned)__shfl_xor((int)wv[4 * c + 0], 32);
        const unsigned pw1 = (unsigned)__shfl_xor((int)wv[4 * c + 1], 32);
        const unsigned pw2 = (unsigned)__shfl_xor((int)wv[4 * c + 2], 32);
        const unsigned pw3 = (unsigned)__shfl_xor((int)wv[4 * c + 3], 32);
        pa[tt][c][0] = hi ? pw2 : wv[4 * c + 0];
        pa[tt][c][1] = hi ? pw3 : wv[4 * c + 1];
        pa[tt][c][2] = hi ? wv[4 * c + 2] : pw0;
        pa[tt][c][3] = hi ? wv[4 * c + 3] : pw1;
      }
    }

    // ctx += P @ V : A = P (rows=q), B = V^T rows (=d) from lV
    __builtin_amdgcn_s_setprio(1);
#pragma unroll
    for (int tt = 0; tt < 2; ++tt)
#pragma unroll
      for (int c = 0; c < 2; ++c) {
        u32x4v pw;
        pw.x = pa[tt][c][0]; pw.y = pa[tt][c][1];
        pw.z = pa[tt][c][2]; pw.w = pa[tt][c][3];
        const bf16x8 aP = __builtin_bit_cast(bf16x8, pw);
#pragma unroll
        for (int dt = 0; dt < 2; ++dt) {
          const bf16x8 bV = *reinterpret_cast<const bf16x8*>(
              &lV[(dt * 32 + l31) * 72 + tt * 32 + c * 16 + hi * 8]);
          acc[dt] = __builtin_amdgcn_mfma_f32_32x32x16_bf16(aP, bV, acc[dt], 0, 0, 0);
        }
      }
    __builtin_amdgcn_s_setprio(0);
  }

  // combine half-wave partial sums; broadcast inverse via per-wave LDS
  const float ltot = lsum + __shfl_xor(lsum, 32);
  if (hi == 0) lsumI[w][l31] = 1.0f / ltot;
  u16* Cp = ctx + (size_t)b * (1024 * 1024) + h * 64;
#pragma unroll
  for (int dt = 0; dt < 2; ++dt)
#pragma unroll
    for (int r = 0; r < 16; ++r) {
      const int q = (r & 3) + 8 * (r >> 2) + 4 * hi;
      const float inv = lsumI[w][q];
      Cp[(q0 + q) * 1024 + dt * 32 + l31] = f2bf(acc[dt][r] * inv);
    }
}

// ---------------- driver ------------------------------------------------------
extern "C" void kernel_launch(void* const* d_in, const int* in_sizes, int n_in,
                              void* d_out, int out_size, void* d_ws, size_t ws_size,
                              hipStream_t stream)
{
  (void)in_sizes; (void)n_in; (void)out_size; (void)ws_size;
  const float* X  = (const float*)d_in[0];
  const float* Y  = (const float*)d_in[1];
  const float* Wq = (const float*)d_in[2];
  const float* bq = (const float*)d_in[3];
  const float* Wk = (const float*)d_in[4];
  const float* bk = (const float*)d_in[5];
  const float* Wv = (const float*)d_in[6];
  const float* bv = (const float*)d_in[7];
  const float* Wg = (const float*)d_in[8];
  const float* bg = (const float*)d_in[9];
  const float* Wb = (const float*)d_in[10];
  const float* bb = (const float*)d_in[11];
  const float* Wo = (const float*)d_in[12];
  const float* bo = (const float*)d_in[13];
  float* out = (float*)d_out;
  char* ws = (char*)d_ws;
  const size_t MB = 1024ull * 1024ull;

  u16* Wqt = (u16*)(ws + 0 * MB);
  u16* Wkt = (u16*)(ws + 2 * MB);
  u16* Wvt = (u16*)(ws + 4 * MB);
  u16* Wcn = (u16*)(ws + 6 * MB);    // Wc = 8*Wg+Wb, non-transposed bf16
  u16* Wot = (u16*)(ws + 8 * MB);
  u16* Wcot = (u16*)(ws + 10 * MB);  // (Wc @ Wo)^T bf16
  u16* Xb = (u16*)(ws + 12 * MB);
  u16* Yb = (u16*)(ws + 28 * MB);   // original Y bf16; later reused for Y_new bf16
  u16* Qb = (u16*)(ws + 44 * MB);
  u16* Kb = (u16*)(ws + 60 * MB);
  u16* Vt = (u16*)(ws + 76 * MB);
  u16* Cx = (u16*)(ws + 92 * MB);
  float* bqs = (float*)(ws + 108 * MB);
  float* bcs = (float*)(ws + 108 * MB + 4096);
  float* bco = (float*)(ws + 108 * MB + 8192);
  const int NEL = 8 * 1024 * 1024;

  prep_w<<<dim3(32, 32, 5), dim3(32, 8), 0, stream>>>(Wq, Wk, Wv, Wg, Wb, Wo,
                                                      Wqt, Wkt, Wvt, Wcn, Wot);
  prep_b<<<4, 256, 0, stream>>>(bq, bg, bb, bqs, bcs);
  cvt2_bf16<<<2048, 256, 0, stream>>>(X, Xb, Y, Yb, NEL);

  // pass 1: queries from X, kv from Y -> Y_new.
  // jobs: Q1, K1, V1(Vt), Wcot=(Wc@Wo)^T (64 blks), bias_dot (256 blks)
  gemm3_k<<<1856, 256, 0, stream>>>(Xb, Wqt, bqs, Qb,
                                    Yb, Wkt, bk, Kb,
                                    Yb, Wvt, bv, Vt,
                                    Wot, Wcn, Wcot,
                                    bcs, bo, bco);
  attn_k<<<dim3(1024), 256, 0, stream>>>(Qb, Kb, Vt, nullptr, Cx);
  gemm_k<1><<<512, 256, 0, stream>>>(Cx, Wcot, bco, Yb, out + NEL);   // Y_new (f32+bf16)

  // pass 2: queries from Y_new, kv from X -> X_new
  gemm3_k<<<1536, 256, 0, stream>>>(Yb, Wqt, bqs, Qb,
                                    Xb, Wkt, bk, Kb,
                                    Xb, Wvt, bv, Vt,
                                    nullptr, nullptr, nullptr,
                                    nullptr, nullptr, nullptr);
  attn_k<<<dim3(1024), 256, 0, stream>>>(Qb, Kb, Vt, nullptr, Cx);
  gemm_k<3><<<512, 256, 0, stream>>>(Cx, Wcot, bco, nullptr, out);    // X_new (f32)
}

// Round 14
// 283.318 us; speedup vs baseline: 2.2515x; 1.0105x over previous
//
#include <hip/hip_runtime.h>

typedef unsigned short u16;
typedef __bf16 bf16x8 __attribute__((ext_vector_type(8)));
typedef float f32x4 __attribute__((ext_vector_type(4)));
typedef float f32x16 __attribute__((ext_vector_type(16)));
typedef u16 u16x4 __attribute__((ext_vector_type(4)));
typedef unsigned int u32x4v __attribute__((ext_vector_type(4)));

#define LOG2E_OVER_8 0.18033688011112043f

__device__ __forceinline__ u16 f2bf(float f) {
  union { float f; unsigned int u; } x{f};
  unsigned int r = (x.u + 0x7fffu + ((x.u >> 16) & 1u)) >> 16;
  return (u16)r;
}

__device__ __forceinline__ float bf2f(u16 v) {
  union { unsigned int u; float f; } x;
  x.u = ((unsigned int)v) << 16;
  return x.f;
}

__device__ __forceinline__ unsigned cvtpk(float a, float b) {
  unsigned r;
  asm("v_cvt_pk_bf16_f32 %0, %1, %2" : "=v"(r) : "v"(a), "v"(b));
  return r;
}

__device__ __forceinline__ void gld16(const void* g, void* l) {
  __builtin_amdgcn_global_load_lds((const __attribute__((address_space(1))) unsigned int*)g,
                                   (__attribute__((address_space(3))) unsigned int*)l,
                                   16, 0, 0);
}

// ---------------- weight prep -------------------------------------------------
// m=0: Wqt = (Wq*log2e/8)^T   m=1: Wkt = Wk^T   m=2: Wvt = Wv^T
// m=3: Wcn = 8*Wg + Wbeta, NON-transposed bf16   m=4: Wot = Wo^T
__global__ void prep_w(const float* __restrict__ Wq, const float* __restrict__ Wk,
                       const float* __restrict__ Wv, const float* __restrict__ Wg,
                       const float* __restrict__ Wb, const float* __restrict__ Wo,
                       u16* __restrict__ Wqt, u16* __restrict__ Wkt, u16* __restrict__ Wvt,
                       u16* __restrict__ Wcn, u16* __restrict__ Wot)
{
  __shared__ float tile[32][33];
  const int m = blockIdx.z;
  const int nb = blockIdx.x * 32, kb = blockIdx.y * 32;
  const int tx = threadIdx.x, ty = threadIdx.y;
  const float* src = (m == 0) ? Wq : (m == 1) ? Wk : (m == 2) ? Wv : (m == 3) ? Wg : Wo;
  u16* dst = (m == 0) ? Wqt : (m == 1) ? Wkt : (m == 2) ? Wvt : (m == 3) ? Wcn : Wot;
#pragma unroll
  for (int i = 0; i < 4; ++i) {
    const int k = kb + ty + i * 8;
    float v = src[k * 1024 + nb + tx];
    if (m == 3) v = 8.0f * v + Wb[k * 1024 + nb + tx];
    if (m == 0) v *= LOG2E_OVER_8;
    if (m == 3) dst[k * 1024 + nb + tx] = f2bf(v);   // direct, non-transposed
    else        tile[ty + i * 8][tx] = v;
  }
  __syncthreads();
  if (m != 3) {
#pragma unroll
    for (int i = 0; i < 4; ++i) {
      const int r = ty + i * 8;
      dst[(nb + r) * 1024 + kb + tx] = f2bf(tile[tx][r]);
    }
  }
}

__global__ void prep_b(const float* __restrict__ bq, const float* __restrict__ bg,
                       const float* __restrict__ bb,
                       float* __restrict__ bqs, float* __restrict__ bcs)
{
  const int i = blockIdx.x * 256 + threadIdx.x;
  if (i < 1024) {
    bqs[i] = bq[i] * LOG2E_OVER_8;
    bcs[i] = 8.0f * bg[i] + bb[i];
  }
}

// ---------------- f32 -> bf16 convert (both tensors, one dispatch) -----------
__global__ void cvt2_bf16(const float* __restrict__ in0, u16* __restrict__ out0,
                          const float* __restrict__ in1, u16* __restrict__ out1, int n)
{
  int i = (blockIdx.x * blockDim.x + threadIdx.x) * 4;
  const int stride = gridDim.x * blockDim.x * 4;
  for (; i < n; i += stride) {
    const float4 v0 = *reinterpret_cast<const float4*>(in0 + i);
    u16x4 o0;
    o0.x = f2bf(v0.x); o0.y = f2bf(v0.y); o0.z = f2bf(v0.z); o0.w = f2bf(v0.w);
    *reinterpret_cast<u16x4*>(out0 + i) = o0;
    const float4 v1 = *reinterpret_cast<const float4*>(in1 + i);
    u16x4 o1;
    o1.x = f2bf(v1.x); o1.y = f2bf(v1.y); o1.z = f2bf(v1.z); o1.w = f2bf(v1.w);
    *reinterpret_cast<u16x4*>(out1 + i) = o1;
  }
}

// ---------------- GEMM body: C[NB*128 x 1024] = A @ Bt^T + bias ---------------
// BK=64 with XOR-swizzled LDS (G21 both-sides pattern): gld16 dest stays
// LINEAR; per-lane global SOURCE col16 is pre-swizzled (col ^ row&7); fragment
// reads apply the same XOR -> conflict-free (verified: SQ_LDS_BANK_CONFLICT=0).
// EPI: 0 = bf16 out; 1 = fp32 + bf16 out; 2 = bf16 out transposed per head
//      Vt[b][h][d][s]; 3 = fp32 out only; 4 = bf16 out, NO bias.
template<int EPI, int NB>
__device__ __forceinline__ void gemm_body(int bid0, u16* lA, u16* lB,
                                          const u16* __restrict__ A,
                                          const u16* __restrict__ Bt,
                                          const float* __restrict__ bias,
                                          u16* __restrict__ outb, float* __restrict__ outf)
{
  int bid = (bid0 & 7) * NB + (bid0 >> 3);   // XCD-contiguous row bands (grid%8==0)
  const int row0 = (bid >> 3) * 128;
  const int col0 = (bid & 7) * 128;
  const int t = threadIdx.x;
  const int w = t >> 6, lane = t & 63;
  const int l15 = lane & 15, l4 = lane >> 4;
  const int wr = w >> 1, wc = w & 1;
  const int l7 = l15 & 7;

  // staging: 1024 16B-chunks per 128x64 tile; thread t owns c = k2*256+t.
  // row = c>>3, source col16 pre-swizzled by row&7 (LDS dest stays linear).
  const u16* gA[4];
  const u16* gB[4];
#pragma unroll
  for (int k2 = 0; k2 < 4; ++k2) {
    const int c = k2 * 256 + t;
    const int r = c >> 3;
    const int sc = ((c & 7) ^ (r & 7)) * 8;
    gA[k2] = A + (row0 + r) * 1024 + sc;
    gB[k2] = Bt + (col0 + r) * 1024 + sc;
  }

  f32x4 acc[4][4] = {};

  for (int kt = 0; kt < 1024; kt += 64) {
#pragma unroll
    for (int k2 = 0; k2 < 4; ++k2) {
      gld16(gA[k2] + kt, lA + (k2 * 256 + w * 64) * 8);
      gld16(gB[k2] + kt, lB + (k2 * 256 + w * 64) * 8);
    }
    __syncthreads();
    bf16x8 aF[4][2], bF[4][2];
#pragma unroll
    for (int m = 0; m < 4; ++m)
#pragma unroll
      for (int ks = 0; ks < 2; ++ks)
        aF[m][ks] = *reinterpret_cast<const bf16x8*>(
            &lA[(wr * 64 + m * 16 + l15) * 64 + ((ks * 4 + l4) ^ l7) * 8]);
#pragma unroll
    for (int n = 0; n < 4; ++n)
#pragma unroll
      for (int ks = 0; ks < 2; ++ks)
        bF[n][ks] = *reinterpret_cast<const bf16x8*>(
            &lB[(wc * 64 + n * 16 + l15) * 64 + ((ks * 4 + l4) ^ l7) * 8]);
#pragma unroll
    for (int m = 0; m < 4; ++m)
#pragma unroll
      for (int n = 0; n < 4; ++n) {
        acc[m][n] = __builtin_amdgcn_mfma_f32_16x16x32_bf16(aF[m][0], bF[n][0], acc[m][n], 0, 0, 0);
        acc[m][n] = __builtin_amdgcn_mfma_f32_16x16x32_bf16(aF[m][1], bF[n][1], acc[m][n], 0, 0, 0);
      }
    __syncthreads();
  }

  float bv[4];
#pragma unroll
  for (int n = 0; n < 4; ++n)
    bv[n] = (EPI == 4) ? 0.0f : bias[col0 + wc * 64 + n * 16 + l15];
#pragma unroll
  for (int m = 0; m < 4; ++m) {
#pragma unroll
    for (int n = 0; n < 4; ++n) {
      const int c = col0 + wc * 64 + n * 16 + l15;
#pragma unroll
      for (int j = 0; j < 4; ++j) {
        const int r = row0 + wr * 64 + m * 16 + l4 * 4 + j;
        const float v = acc[m][n][j] + bv[n];
        if constexpr (EPI == 0 || EPI == 4) {
          outb[r * 1024 + c] = f2bf(v);
        } else if constexpr (EPI == 1) {
          outf[r * 1024 + c] = v;
          outb[r * 1024 + c] = f2bf(v);
        } else if constexpr (EPI == 2) {
          const int bi = r >> 10, s = r & 1023;
          const int h = c >> 6, d = c & 63;
          outb[((bi * 16 + h) * 64 + d) * 1024 + s] = f2bf(v);
        } else {
          outf[r * 1024 + c] = v;
        }
      }
    }
  }
}

// bias job: bco[n] = dot(bcs, Wot-row-n) + bo[n]; 256 blocks, wave per row
__device__ __forceinline__ void bias_body(int bb, const float* __restrict__ bcs,
                                          const u16* __restrict__ Wot,
                                          const float* __restrict__ bo,
                                          float* __restrict__ bco)
{
  const int t = threadIdx.x, w = t >> 6, l = t & 63;
  const int n = bb * 4 + w;
  const u16* row = Wot + n * 1024;
  float a = 0.f;
#pragma unroll
  for (int i = 0; i < 16; ++i) a += bcs[l + 64 * i] * bf2f(row[l + 64 * i]);
#pragma unroll
  for (int d = 1; d < 64; d <<= 1) a += __shfl_xor(a, d);
  if (l == 0) bco[n] = a + bo[n];
}

template<int EPI, int NB = 64>
__global__ __launch_bounds__(256, 3)
void gemm_k(const u16* __restrict__ A, const u16* __restrict__ Bt,
            const float* __restrict__ bias,
            u16* __restrict__ outb, float* __restrict__ outf)
{
  __shared__ u16 lA[128 * 64];
  __shared__ u16 lB[128 * 64];
  gemm_body<EPI, NB>((int)blockIdx.x, lA, lB, A, Bt, bias, outb, outf);
}

// merged Q/K/V (+ job 3: Wcot = (Wc@Wo)^T, 64 blocks; + job 4: bias_dot,
// 256 blocks). grid = 1856 (pass 1) or 1536 (pass 2).
__global__ __launch_bounds__(256, 3)
void gemm3_k(const u16* __restrict__ A0, const u16* __restrict__ B0,
             const float* __restrict__ c0, u16* __restrict__ o0,
             const u16* __restrict__ A1, const u16* __restrict__ B1,
             const float* __restrict__ c1, u16* __restrict__ o1,
             const u16* __restrict__ A2, const u16* __restrict__ B2,
             const float* __restrict__ c2, u16* __restrict__ o2,
             const u16* __restrict__ A3, const u16* __restrict__ B3,
             u16* __restrict__ o3,
             const float* __restrict__ bcs, const float* __restrict__ bo,
             float* __restrict__ bco)
{
  __shared__ u16 lA[128 * 64];
  __shared__ u16 lB[128 * 64];
  const int id = (int)blockIdx.x;
  if (id < 512)       gemm_body<0, 64>(id,        lA, lB, A0, B0, c0, o0, nullptr);
  else if (id < 1024) gemm_body<0, 64>(id - 512,  lA, lB, A1, B1, c1, o1, nullptr);
  else if (id < 1536) gemm_body<2, 64>(id - 1024, lA, lB, A2, B2, c2, o2, nullptr);
  else if (id < 1600) gemm_body<4, 8>(id - 1536,  lA, lB, A3, B3, nullptr, o3, nullptr);
  else                bias_body(id - 1600, bcs, A3, bo, bco);   // A3 = Wot
}

// ---------------- flash attention v7: no-max softmax + permlane32_swap --------
// 32x32x16 MFMAs, swapped operands: S^T = mfma(K,Q), lane holds 16 scores for
// q=lane&31, kv=(r&3)+8*(r>>2)+4*(lane>>5). No running max (|S| bounded, exp2
// in-range); divide by sum at the end. Half-wave exchange via
// v_permlane32_swap_b32 (T12): one swap produces BOTH A-frag words —
// a' = {a.lo, b.lo}, b' = {a.hi, b.hi} — replacing 16 ds_permute + 16 cndmask
// (LDS-pipe latency on the critical path) with 8 VALU ops.
// K/V LDS staging + T14 async-stage + XCD co-location.
__global__ __launch_bounds__(256, 4)
void attn_k(const u16* __restrict__ Q, const u16* __restrict__ K,
            const u16* __restrict__ Vt, const u16* __restrict__ ctx_unused,
            u16* __restrict__ ctx)
{
  __shared__ u16 lK[64 * 72];
  __shared__ u16 lV[64 * 72];
  __shared__ float lsumI[4][32];
  const int id = (int)blockIdx.x;
  const int xcd = id & 7, o = id >> 3;
  const int pair = xcd * 16 + (o >> 3);   // 16 (b,h) pairs per XCD
  const int qt = o & 7;
  const int b = pair >> 4, h = pair & 15;
  const int t = threadIdx.x, w = t >> 6, lane = t & 63;
  const int l31 = lane & 31, hi = lane >> 5;
  const int q0 = qt * 128 + w * 32;
  const u16* Qp = Q + (size_t)b * (1024 * 1024) + h * 64;
  const u16* Kp = K + (size_t)b * (1024 * 1024) + h * 64;
  const u16* Vp = Vt + (size_t)(b * 16 + h) * (64 * 1024);

  // staging slots: thread t owns rows r0 and r0+32, 16B chunk c0 (u16 units)
  const int r0 = t >> 3, c0 = (t & 7) * 8;

  // Q fragments (B-operand: lane holds Q[q=l31][d = ks*16 + hi*8 + i])
  bf16x8 bQ[4];
#pragma unroll
  for (int ks = 0; ks < 4; ++ks)
    bQ[ks] = *reinterpret_cast<const bf16x8*>(&Qp[(q0 + l31) * 1024 + ks * 16 + hi * 8]);

  f32x16 acc[2] = {};
  float lsum = 0.f;

  // prologue: issue tile-0 loads
  bf16x8 sK0, sK1, sV0, sV1;
  sK0 = *reinterpret_cast<const bf16x8*>(&Kp[(r0) * 1024 + c0]);
  sK1 = *reinterpret_cast<const bf16x8*>(&Kp[(r0 + 32) * 1024 + c0]);
  sV0 = *reinterpret_cast<const bf16x8*>(&Vp[r0 * 1024 + c0]);
  sV1 = *reinterpret_cast<const bf16x8*>(&Vp[(r0 + 32) * 1024 + c0]);

  for (int it = 0; it < 16; ++it) {
    const int kv0 = it * 64;
    __syncthreads();   // all waves done reading previous tile
    *reinterpret_cast<bf16x8*>(&lK[r0 * 72 + c0]) = sK0;
    *reinterpret_cast<bf16x8*>(&lK[(r0 + 32) * 72 + c0]) = sK1;
    *reinterpret_cast<bf16x8*>(&lV[r0 * 72 + c0]) = sV0;
    *reinterpret_cast<bf16x8*>(&lV[(r0 + 32) * 72 + c0]) = sV1;
    __syncthreads();   // tile ready
    if (it + 1 < 16) {  // issue next tile: in flight during the whole compute
      const int nk = kv0 + 64;
      sK0 = *reinterpret_cast<const bf16x8*>(&Kp[(nk + r0) * 1024 + c0]);
      sK1 = *reinterpret_cast<const bf16x8*>(&Kp[(nk + r0 + 32) * 1024 + c0]);
      sV0 = *reinterpret_cast<const bf16x8*>(&Vp[r0 * 1024 + nk + c0]);
      sV1 = *reinterpret_cast<const bf16x8*>(&Vp[(r0 + 32) * 1024 + nk + c0]);
    }

    // S^T = K Q^T: rows=kv (regs), cols=q (lanes). 2 kv-tiles of 32.
    f32x16 sS[2] = {};
    __builtin_amdgcn_s_setprio(1);
#pragma unroll
    for (int tt = 0; tt < 2; ++tt) {
#pragma unroll
      for (int ks = 0; ks < 4; ++ks) {
        const bf16x8 aK = *reinterpret_cast<const bf16x8*>(
            &lK[(tt * 32 + l31) * 72 + ks * 16 + hi * 8]);
        sS[tt] = __builtin_amdgcn_mfma_f32_32x32x16_bf16(aK, bQ[ks], sS[tt], 0, 0, 0);
      }
    }
    __builtin_amdgcn_s_setprio(0);

    // P = exp2(S) directly; pack to bf16 pairs; permlane32_swap -> PV A-frags
    unsigned pa[2][2][4];
#pragma unroll
    for (int tt = 0; tt < 2; ++tt) {
      float p[16];
      float s0 = 0.f, s1 = 0.f, s2 = 0.f, s3 = 0.f;
#pragma unroll
      for (int r = 0; r < 16; r += 4) {
        p[r]     = __builtin_amdgcn_exp2f(sS[tt][r]);
        p[r + 1] = __builtin_amdgcn_exp2f(sS[tt][r + 1]);
        p[r + 2] = __builtin_amdgcn_exp2f(sS[tt][r + 2]);
        p[r + 3] = __builtin_amdgcn_exp2f(sS[tt][r + 3]);
        s0 += p[r]; s1 += p[r + 1]; s2 += p[r + 2]; s3 += p[r + 3];
      }
      lsum += (s0 + s1) + (s2 + s3);
      unsigned wv[8];
#pragma unroll
      for (int i = 0; i < 8; ++i) wv[i] = cvtpk(p[2 * i], p[2 * i + 1]);
#pragma unroll
      for (int c = 0; c < 2; ++c) {
        unsigned a0 = wv[4 * c + 0], b0 = wv[4 * c + 2];
        unsigned a1 = wv[4 * c + 1], b1 = wv[4 * c + 3];
        // after swap: a' = {a.lanes0-31, b.lanes0-31}, b' = {a.lanes32-63, b.lanes32-63}
        asm("v_permlane32_swap_b32 %0, %1" : "+v"(a0), "+v"(b0));
        asm("v_permlane32_swap_b32 %0, %1" : "+v"(a1), "+v"(b1));
        pa[tt][c][0] = a0;
        pa[tt][c][1] = a1;
        pa[tt][c][2] = b0;
        pa[tt][c][3] = b1;
      }
    }

    // ctx += P @ V : A = P (rows=q), B = V^T rows (=d) from lV
    __builtin_amdgcn_s_setprio(1);
#pragma unroll
    for (int tt = 0; tt < 2; ++tt)
#pragma unroll
      for (int c = 0; c < 2; ++c) {
        u32x4v pw;
        pw.x = pa[tt][c][0]; pw.y = pa[tt][c][1];
        pw.z = pa[tt][c][2]; pw.w = pa[tt][c][3];
        const bf16x8 aP = __builtin_bit_cast(bf16x8, pw);
#pragma unroll
        for (int dt = 0; dt < 2; ++dt) {
          const bf16x8 bV = *reinterpret_cast<const bf16x8*>(
              &lV[(dt * 32 + l31) * 72 + tt * 32 + c * 16 + hi * 8]);
          acc[dt] = __builtin_amdgcn_mfma_f32_32x32x16_bf16(aP, bV, acc[dt], 0, 0, 0);
        }
      }
    __builtin_amdgcn_s_setprio(0);
  }

  // combine half-wave partial sums; broadcast inverse via per-wave LDS
  const float ltot = lsum + __shfl_xor(lsum, 32);
  if (hi == 0) lsumI[w][l31] = 1.0f / ltot;
  u16* Cp = ctx + (size_t)b * (1024 * 1024) + h * 64;
#pragma unroll
  for (int dt = 0; dt < 2; ++dt)
#pragma unroll
    for (int r = 0; r < 16; ++r) {
      const int q = (r & 3) + 8 * (r >> 2) + 4 * hi;
      const float inv = lsumI[w][q];
      Cp[(q0 + q) * 1024 + dt * 32 + l31] = f2bf(acc[dt][r] * inv);
    }
}

// ---------------- driver ------------------------------------------------------
extern "C" void kernel_launch(void* const* d_in, const int* in_sizes, int n_in,
                              void* d_out, int out_size, void* d_ws, size_t ws_size,
                              hipStream_t stream)
{
  (void)in_sizes; (void)n_in; (void)out_size; (void)ws_size;
  const float* X  = (const float*)d_in[0];
  const float* Y  = (const float*)d_in[1];
  const float* Wq = (const float*)d_in[2];
  const float* bq = (const float*)d_in[3];
  const float* Wk = (const float*)d_in[4];
  const float* bk = (const float*)d_in[5];
  const float* Wv = (const float*)d_in[6];
  const float* bv = (const float*)d_in[7];
  const float* Wg = (const float*)d_in[8];
  const float* bg = (const float*)d_in[9];
  const float* Wb = (const float*)d_in[10];
  const float* bb = (const float*)d_in[11];
  const float* Wo = (const float*)d_in[12];
  const float* bo = (const float*)d_in[13];
  float* out = (float*)d_out;
  char* ws = (char*)d_ws;
  const size_t MB = 1024ull * 1024ull;

  u16* Wqt = (u16*)(ws + 0 * MB);
  u16* Wkt = (u16*)(ws + 2 * MB);
  u16* Wvt = (u16*)(ws + 4 * MB);
  u16* Wcn = (u16*)(ws + 6 * MB);    // Wc = 8*Wg+Wb, non-transposed bf16
  u16* Wot = (u16*)(ws + 8 * MB);
  u16* Wcot = (u16*)(ws + 10 * MB);  // (Wc @ Wo)^T bf16
  u16* Xb = (u16*)(ws + 12 * MB);
  u16* Yb = (u16*)(ws + 28 * MB);   // original Y bf16; later reused for Y_new bf16
  u16* Qb = (u16*)(ws + 44 * MB);
  u16* Kb = (u16*)(ws + 60 * MB);
  u16* Vt = (u16*)(ws + 76 * MB);
  u16* Cx = (u16*)(ws + 92 * MB);
  float* bqs = (float*)(ws + 108 * MB);
  float* bcs = (float*)(ws + 108 * MB + 4096);
  float* bco = (float*)(ws + 108 * MB + 8192);
  const int NEL = 8 * 1024 * 1024;

  prep_w<<<dim3(32, 32, 5), dim3(32, 8), 0, stream>>>(Wq, Wk, Wv, Wg, Wb, Wo,
                                                      Wqt, Wkt, Wvt, Wcn, Wot);
  prep_b<<<4, 256, 0, stream>>>(bq, bg, bb, bqs, bcs);
  cvt2_bf16<<<2048, 256, 0, stream>>>(X, Xb, Y, Yb, NEL);

  // pass 1: queries from X, kv from Y -> Y_new.
  // jobs: Q1, K1, V1(Vt), Wcot=(Wc@Wo)^T (64 blks), bias_dot (256 blks)
  gemm3_k<<<1856, 256, 0, stream>>>(Xb, Wqt, bqs, Qb,
                                    Yb, Wkt, bk, Kb,
                                    Yb, Wvt, bv, Vt,
                                    Wot, Wcn, Wcot,
                                    bcs, bo, bco);
  attn_k<<<dim3(1024), 256, 0, stream>>>(Qb, Kb, Vt, nullptr, Cx);
  gemm_k<1><<<512, 256, 0, stream>>>(Cx, Wcot, bco, Yb, out + NEL);   // Y_new (f32+bf16)

  // pass 2: queries from Y_new, kv from X -> X_new
  gemm3_k<<<1536, 256, 0, stream>>>(Yb, Wqt, bqs, Qb,
                                    Xb, Wkt, bk, Kb,
                                    Xb, Wvt, bv, Vt,
                                    nullptr, nullptr, nullptr,
                                    nullptr, nullptr, nullptr);
  attn_k<<<dim3(1024), 256, 0, stream>>>(Qb, Kb, Vt, nullptr, Cx);
  gemm_k<3><<<512, 256, 0, stream>>>(Cx, Wcot, bco, nullptr, out);    // X_new (f32)
}